// Round 14
// baseline (368.201 us; speedup 1.0000x reference)
//
#include <hip/hip_runtime.h>
#include <hip/hip_bf16.h>

#define B_ 2
#define S_ 2048
#define D_ 1024
#define H_ 16
#define HD_ 64

typedef short bf16x8 __attribute__((ext_vector_type(8)));
typedef float f32x4 __attribute__((ext_vector_type(4)));

typedef __attribute__((address_space(3))) void lds_void;
typedef const __attribute__((address_space(1))) void gbl_void;

__device__ __forceinline__ f32x4 mfma16(bf16x8 a, bf16x8 b, f32x4 c) {
    return __builtin_amdgcn_mfma_f32_16x16x32_bf16(a, b, c, 0, 0, 0);
}

__device__ __forceinline__ bf16x8 ldb8(const __hip_bfloat16* p) {
    return *reinterpret_cast<const bf16x8*>(p);
}

// ---------------- fp32 -> bf16 conversion ----------------
__global__ __launch_bounds__(256) void conv_kernel(const float* __restrict__ src,
                                                   __hip_bfloat16* __restrict__ dst, int n4) {
    int i = blockIdx.x * 256 + threadIdx.x;
    if (i >= n4) return;
    float4 f = reinterpret_cast<const float4*>(src)[i];
    union { __hip_bfloat16 h[4]; ushort4 u; } cv;
    cv.h[0] = __float2bfloat16(f.x);
    cv.h[1] = __float2bfloat16(f.y);
    cv.h[2] = __float2bfloat16(f.z);
    cv.h[3] = __float2bfloat16(f.w);
    reinterpret_cast<ushort4*>(dst)[i] = cv.u;
}

// ---------------- GEMM (m97 structure): global_load_lds w16, linear LDS ----------------
template <int MODE>
__global__ __launch_bounds__(256) void gemm_bt(
    const __hip_bfloat16* __restrict__ X, const __hip_bfloat16* __restrict__ Wt,
    const float* __restrict__ bias0, const float* __restrict__ bias1,
    const float* __restrict__ bias2,
    __hip_bfloat16* __restrict__ Yq, __hip_bfloat16* __restrict__ Yk,
    __hip_bfloat16* __restrict__ Yv, float* __restrict__ Yo,
    int M, int N, int K) {
    __shared__ __hip_bfloat16 As[128 * 32];
    __shared__ __hip_bfloat16 Bs[128 * 32];

    const int ntn = N >> 7;
    const int nwg = (M >> 7) * ntn;
    const int cpx = nwg >> 3;
    const int bid = blockIdx.x;
    const int lg = (bid & 7) * cpx + (bid >> 3);
    const int tm = lg / ntn;
    const int tn = lg % ntn;
    const int t = threadIdx.x;
    const int w = t >> 6, l = t & 63, g = l >> 4, c = l & 15;
    const int wr = w >> 1, wc = w & 1;

    const int lrow16 = l >> 2;
    const int lcol = (l & 3) * 8;

    const int r0 = w * 32 + lrow16;
    const int r1 = w * 32 + 16 + lrow16;
    const size_t xg0 = (size_t)(tm * 128 + r0) * K + lcol;
    const size_t xg1 = (size_t)(tm * 128 + r1) * K + lcol;
    const size_t wg0 = (size_t)(tn * 128 + r0) * K + lcol;
    const size_t wg1 = (size_t)(tn * 128 + r1) * K + lcol;

    f32x4 acc[4][4] = {};

    for (int k0 = 0; k0 < K; k0 += 32) {
        __syncthreads();
        __builtin_amdgcn_global_load_lds((gbl_void*)(X + xg0 + k0),
                                         (lds_void*)(As + (w * 32) * 32), 16, 0, 0);
        __builtin_amdgcn_global_load_lds((gbl_void*)(X + xg1 + k0),
                                         (lds_void*)(As + (w * 32 + 16) * 32), 16, 0, 0);
        __builtin_amdgcn_global_load_lds((gbl_void*)(Wt + wg0 + k0),
                                         (lds_void*)(Bs + (w * 32) * 32), 16, 0, 0);
        __builtin_amdgcn_global_load_lds((gbl_void*)(Wt + wg1 + k0),
                                         (lds_void*)(Bs + (w * 32 + 16) * 32), 16, 0, 0);
        __syncthreads();

        bf16x8 am[4], bn[4];
#pragma unroll
        for (int mi = 0; mi < 4; ++mi) am[mi] = ldb8(&As[(wr * 64 + mi * 16 + c) * 32 + g * 8]);
#pragma unroll
        for (int ni = 0; ni < 4; ++ni) bn[ni] = ldb8(&Bs[(wc * 64 + ni * 16 + c) * 32 + g * 8]);
#pragma unroll
        for (int mi = 0; mi < 4; ++mi)
#pragma unroll
            for (int ni = 0; ni < 4; ++ni)
                acc[mi][ni] = mfma16(am[mi], bn[ni], acc[mi][ni]);
    }

#pragma unroll
    for (int mi = 0; mi < 4; ++mi) {
        const int mbase = tm * 128 + wr * 64 + mi * 16 + g * 4;
#pragma unroll
        for (int ni = 0; ni < 4; ++ni) {
            const int n = tn * 128 + wc * 64 + ni * 16 + c;
#pragma unroll
            for (int r = 0; r < 4; ++r) {
                const int mm = mbase + r;
                float v = acc[mi][ni][r];
                if (MODE == 0) {
                    const float* bp = (n < 1024) ? bias0 : (n < 2048) ? bias1 : bias2;
                    const int nn = n & 1023;
                    v += bp[nn];
                    const int b = mm >> 11, s = mm & 2047;
                    const int h = nn >> 6, hd = nn & 63;
                    const size_t bh = (size_t)(b * H_ + h);
                    const __hip_bfloat16 bvv = __float2bfloat16(v);
                    if (n < 2048) {
                        __hip_bfloat16* dst = (n < 1024) ? Yq : Yk;
                        dst[(bh * S_ + s) * HD_ + hd] = bvv;
                    } else {
                        Yv[(bh * HD_ + hd) * S_ + s] = bvv;
                    }
                } else {
                    Yo[(size_t)mm * N + n] = v + bias0[n];
                }
            }
        }
    }
}

// K stage: byte(row*128 + (X ^ ((row&7)<<4))) = K[row][X/2]. (r11-verified)
#define STAGE_K(dstc, t8v) do {                                                   \
    const int kt_ = (t8v) * 256;                                                  \
    _Pragma("unroll")                                                             \
    for (int i_ = 0; i_ < 4; ++i_) {                                              \
        const int chunk_ = w * 4 + i_;                                            \
        const int row_ = 8 * chunk_ + (l >> 3);                                   \
        const int col_ = ((l & 7) ^ ((l >> 3) & 7)) * 8;                          \
        __builtin_amdgcn_global_load_lds(                                         \
            (gbl_void*)(Kb + (size_t)(kt_ + row_) * HD_ + col_),                  \
            (lds_void*)((dstc) + chunk_ * 1024), 16, 0, 0);                       \
    }                                                                             \
} while (0)

// V stage: byte(row*512 + (X ^ ((row&7)<<4))) = V[row][kt + X/2]. (r11-verified)
#define STAGE_V(dstc, t8v) do {                                                   \
    const int kt_ = (t8v) * 256;                                                  \
    _Pragma("unroll")                                                             \
    for (int i_ = 0; i_ < 4; ++i_) {                                              \
        const int chunk_ = w * 4 + i_;                                            \
        const int row_ = 2 * chunk_ + (l >> 5);                                   \
        const int col_ = ((l & 31) ^ (row_ & 7)) * 8;                             \
        __builtin_amdgcn_global_load_lds(                                         \
            (gbl_void*)(Vb + (size_t)row_ * S_ + kt_ + col_),                     \
            (lds_void*)((dstc) + chunk_ * 1024), 16, 0, 0);                       \
    }                                                                             \
} while (0)

// ---------------- fused attention: r11 two-sweep pipeline + clean vmcnt ----------------
// 2048 blocks x 8 waves, 2 blocks/CU. Pass 2's vmcnt queue holds ONLY V loads
// (probs stores deferred to an end burst); V(0) prefetched across the seam.
__global__ __launch_bounds__(512) void attn_kernel(
    const __hip_bfloat16* __restrict__ Qh, const __hip_bfloat16* __restrict__ Kh,
    const __hip_bfloat16* __restrict__ Vt, const float* __restrict__ mask,
    float* __restrict__ probs, __hip_bfloat16* __restrict__ ctx) {
    union SMem {
        char Kdb[2][32768];      // K/V tile double-buffer (64 KB)
        float Cred[8][16][68];   // epilogue reduce (aliases)
    };
    __shared__ SMem sm;
    __shared__ float msk[2048];
    __shared__ float sred[8][32];
    __shared__ float invsh[32];

    const int bid = blockIdx.x;
    const int lg = (bid & 7) * 256 + (bid >> 3);
    const int qt = lg & 63;
    const int bh = lg >> 6;
    const int b = bh >> 4, h = bh & 15;
    const int t = threadIdx.x;
    const int w = t >> 6, l = t & 63, g = l >> 4, c = l & 15;
    const int q0 = qt * 32;
    const int kw = 32 * w;

    const __hip_bfloat16* Qb = Qh + (size_t)bh * S_ * HD_;
    const __hip_bfloat16* Kb = Kh + (size_t)bh * S_ * HD_;
    const __hip_bfloat16* Vb = Vt + (size_t)bh * HD_ * S_;
    const float* mrow = mask + (size_t)b * S_;

    *reinterpret_cast<float4*>(&msk[t * 4]) =
        *reinterpret_cast<const float4*>(&mrow[t * 4]);

    const bf16x8 aqA0 = ldb8(&Qb[(q0 + c) * HD_ + g * 8]);
    const bf16x8 aqA1 = ldb8(&Qb[(q0 + c) * HD_ + 32 + g * 8]);
    const bf16x8 aqB0 = ldb8(&Qb[(q0 + 16 + c) * HD_ + g * 8]);
    const bf16x8 aqB1 = ldb8(&Qb[(q0 + 16 + c) * HD_ + 32 + g * 8]);

    unsigned int uA[8][2][2], uB[8][2][2];
    float lsumA = 0.f, lsumB = 0.f;

    // ---- pass 1: pipelined K tiles, QK^T + exp, P~ -> regs ----
    STAGE_K(sm.Kdb[0], 0);
#pragma unroll
    for (int t8 = 0; t8 < 8; ++t8) {
        char* cur = sm.Kdb[t8 & 1];
        if (t8 < 7) {
            STAGE_K(sm.Kdb[(t8 & 1) ^ 1], t8 + 1);
            asm volatile("s_waitcnt vmcnt(4)" ::: "memory");
        } else {
            asm volatile("s_waitcnt vmcnt(0)" ::: "memory");
        }
        if (t8 == 0) asm volatile("s_waitcnt lgkmcnt(0)" ::: "memory");
        __builtin_amdgcn_s_barrier();
        __builtin_amdgcn_sched_barrier(0);
        const int kt = t8 * 256;
#pragma unroll
        for (int ss = 0; ss < 2; ++ss) {
            const int krow = kw + ss * 16 + c;
            const char* kb2 = cur + krow * 128;
            const int sw = (krow & 7) << 4;
            const bf16x8 k0 = *reinterpret_cast<const bf16x8*>(kb2 + ((g * 16) ^ sw));
            const bf16x8 k1 = *reinterpret_cast<const bf16x8*>(kb2 + ((64 + g * 16) ^ sw));
            f32x4 aA = {}, aB = {};
            aA = mfma16(k0, aqA0, aA);
            aA = mfma16(k1, aqA1, aA);
            aB = mfma16(k0, aqB0, aB);
            aB = mfma16(k1, aqB1, aB);
            const float4 mk = *reinterpret_cast<const float4*>(&msk[kt + kw + ss * 16 + g * 4]);
            const float pA0 = __expf(aA[0] * 0.125f + mk.x);
            const float pA1 = __expf(aA[1] * 0.125f + mk.y);
            const float pA2 = __expf(aA[2] * 0.125f + mk.z);
            const float pA3 = __expf(aA[3] * 0.125f + mk.w);
            const float pB0 = __expf(aB[0] * 0.125f + mk.x);
            const float pB1 = __expf(aB[1] * 0.125f + mk.y);
            const float pB2 = __expf(aB[2] * 0.125f + mk.z);
            const float pB3 = __expf(aB[3] * 0.125f + mk.w);
            lsumA += (pA0 + pA1) + (pA2 + pA3);
            lsumB += (pB0 + pB1) + (pB2 + pB3);
            union { __hip_bfloat16 hh[2]; unsigned int ui; } w0, w1;
            w0.hh[0] = __float2bfloat16(pA0); w0.hh[1] = __float2bfloat16(pA1);
            w1.hh[0] = __float2bfloat16(pA2); w1.hh[1] = __float2bfloat16(pA3);
            uA[t8][ss][0] = w0.ui; uA[t8][ss][1] = w1.ui;
            w0.hh[0] = __float2bfloat16(pB0); w0.hh[1] = __float2bfloat16(pB1);
            w1.hh[0] = __float2bfloat16(pB2); w1.hh[1] = __float2bfloat16(pB3);
            uB[t8][ss][0] = w0.ui; uB[t8][ss][1] = w1.ui;
        }
        __builtin_amdgcn_sched_barrier(0);
        __builtin_amdgcn_s_barrier();
    }

    // ---- seam: prefetch V(0) BEFORE the reduce; no vmcnt drain here ----
    STAGE_V(sm.Kdb[0], 0);

    lsumA += __shfl_xor(lsumA, 16); lsumA += __shfl_xor(lsumA, 32);
    lsumB += __shfl_xor(lsumB, 16); lsumB += __shfl_xor(lsumB, 32);
    if (g == 0) { sred[w][c] = lsumA; sred[w][16 + c] = lsumB; }
    asm volatile("s_waitcnt lgkmcnt(0)" ::: "memory");
    __builtin_amdgcn_s_barrier();          // raw barrier: keeps V(0) in flight
    __builtin_amdgcn_sched_barrier(0);
    float totA = 0.f, totB = 0.f;
#pragma unroll
    for (int w8 = 0; w8 < 8; ++w8) { totA += sred[w8][c]; totB += sred[w8][16 + c]; }
    const float invA = 1.0f / totA;
    const float invB = 1.0f / totB;
    if (w == 0 && g == 0) { invsh[c] = invA; invsh[16 + c] = invB; }

    // ---- pass 2: pipelined V tiles, PV only (probs deferred) ----
    f32x4 caccA[4] = {}, caccB[4] = {};
    const int src0 = 32 * (g & 1) + c;
    const int src1 = src0 + 16;
    const int sigma = g >> 1;
#pragma unroll
    for (int t8 = 0; t8 < 8; ++t8) {
        const char* cur = sm.Kdb[t8 & 1];
        if (t8 < 7) {
            STAGE_V(sm.Kdb[(t8 & 1) ^ 1], t8 + 1);
            asm volatile("s_waitcnt vmcnt(4)" ::: "memory");
        } else {
            asm volatile("s_waitcnt vmcnt(0)" ::: "memory");
        }
        __builtin_amdgcn_s_barrier();
        __builtin_amdgcn_sched_barrier(0);
        union { unsigned int ui[4]; bf16x8 v; } afA, afB;
        {
            const unsigned int x00 = __shfl(uA[t8][0][0], src0);
            const unsigned int x10 = __shfl(uA[t8][1][0], src0);
            const unsigned int x01 = __shfl(uA[t8][0][1], src0);
            const unsigned int x11 = __shfl(uA[t8][1][1], src0);
            const unsigned int x02 = __shfl(uA[t8][0][0], src1);
            const unsigned int x12 = __shfl(uA[t8][1][0], src1);
            const unsigned int x03 = __shfl(uA[t8][0][1], src1);
            const unsigned int x13 = __shfl(uA[t8][1][1], src1);
            afA.ui[0] = sigma ? x10 : x00;
            afA.ui[1] = sigma ? x11 : x01;
            afA.ui[2] = sigma ? x12 : x02;
            afA.ui[3] = sigma ? x13 : x03;
        }
        {
            const unsigned int x00 = __shfl(uB[t8][0][0], src0);
            const unsigned int x10 = __shfl(uB[t8][1][0], src0);
            const unsigned int x01 = __shfl(uB[t8][0][1], src0);
            const unsigned int x11 = __shfl(uB[t8][1][1], src0);
            const unsigned int x02 = __shfl(uB[t8][0][0], src1);
            const unsigned int x12 = __shfl(uB[t8][1][0], src1);
            const unsigned int x03 = __shfl(uB[t8][0][1], src1);
            const unsigned int x13 = __shfl(uB[t8][1][1], src1);
            afB.ui[0] = sigma ? x10 : x00;
            afB.ui[1] = sigma ? x11 : x01;
            afB.ui[2] = sigma ? x12 : x02;
            afB.ui[3] = sigma ? x13 : x03;
        }
#pragma unroll
        for (int n = 0; n < 4; ++n) {
            const int vrow = n * 16 + c;
            const bf16x8 bv = *reinterpret_cast<const bf16x8*>(
                cur + vrow * 512 + ((64 * w + g * 16) ^ ((vrow & 7) << 4)));
            caccA[n] = mfma16(afA.v, bv, caccA[n]);
            caccB[n] = mfma16(afB.v, bv, caccB[n]);
        }
        __builtin_amdgcn_sched_barrier(0);
        __builtin_amdgcn_s_barrier();
    }

    // ---- cross-wave PV reduce ----
    __syncthreads();
#pragma unroll
    for (int n = 0; n < 4; ++n)
#pragma unroll
        for (int r = 0; r < 4; ++r)
            sm.Cred[w][g * 4 + r][n * 16 + c] = caccA[n][r];
    __syncthreads();
    {
        const int row = t >> 5, col2 = (t & 31) * 2;
        float a0 = 0.f, a1 = 0.f;
#pragma unroll
        for (int w8 = 0; w8 < 8; ++w8) {
            const float2 vv = *reinterpret_cast<const float2*>(&sm.Cred[w8][row][col2]);
            a0 += vv.x; a1 += vv.y;
        }
        const float fin = invsh[row];
        union { __hip_bfloat16 hh[2]; unsigned int ui; } ov;
        ov.hh[0] = __float2bfloat16(a0 * fin);
        ov.hh[1] = __float2bfloat16(a1 * fin);
        *reinterpret_cast<unsigned int*>(
            &ctx[((size_t)b * S_ + q0 + row) * D_ + h * HD_ + col2]) = ov.ui;
    }
    __syncthreads();
#pragma unroll
    for (int n = 0; n < 4; ++n)
#pragma unroll
        for (int r = 0; r < 4; ++r)
            sm.Cred[w][g * 4 + r][n * 16 + c] = caccB[n][r];
    __syncthreads();
    {
        const int row = t >> 5, col2 = (t & 31) * 2;
        float a0 = 0.f, a1 = 0.f;
#pragma unroll
        for (int w8 = 0; w8 < 8; ++w8) {
            const float2 vv = *reinterpret_cast<const float2*>(&sm.Cred[w8][row][col2]);
            a0 += vv.x; a1 += vv.y;
        }
        const float fin = invsh[16 + row];
        union { __hip_bfloat16 hh[2]; unsigned int ui; } ov;
        ov.hh[0] = __float2bfloat16(a0 * fin);
        ov.hh[1] = __float2bfloat16(a1 * fin);
        *reinterpret_cast<unsigned int*>(
            &ctx[((size_t)b * S_ + q0 + 16 + row) * D_ + h * HD_ + col2]) = ov.ui;
    }

    // ---- probs store burst (independent tail; blocks overlap via occupancy) ----
    float* prowA = probs + ((size_t)bh * S_ + q0 + c) * S_;
    float* prowB = prowA + (size_t)16 * S_;
#pragma unroll
    for (int t8 = 0; t8 < 8; ++t8) {
        const int kt = t8 * 256;
#pragma unroll
        for (int ss = 0; ss < 2; ++ss) {
            f32x4 oA, oB;
            oA[0] = __uint_as_float(uA[t8][ss][0] << 16) * invA;
            oA[1] = __uint_as_float(uA[t8][ss][0] & 0xffff0000u) * invA;
            oA[2] = __uint_as_float(uA[t8][ss][1] << 16) * invA;
            oA[3] = __uint_as_float(uA[t8][ss][1] & 0xffff0000u) * invA;
            *reinterpret_cast<f32x4*>(&prowA[kt + kw + ss * 16 + g * 4]) = oA;
            oB[0] = __uint_as_float(uB[t8][ss][0] << 16) * invB;
            oB[1] = __uint_as_float(uB[t8][ss][0] & 0xffff0000u) * invB;
            oB[2] = __uint_as_float(uB[t8][ss][1] << 16) * invB;
            oB[3] = __uint_as_float(uB[t8][ss][1] & 0xffff0000u) * invB;
            *reinterpret_cast<f32x4*>(&prowB[kt + kw + ss * 16 + g * 4]) = oB;
        }
    }
}

// ---------------- launch ----------------
extern "C" void kernel_launch(void* const* d_in, const int* in_sizes, int n_in,
                              void* d_out, int out_size, void* d_ws, size_t ws_size,
                              hipStream_t stream) {
    const float* hs   = (const float*)d_in[0];
    const float* mask = (const float*)d_in[1];
    const float* Wq   = (const float*)d_in[2];
    const float* bq   = (const float*)d_in[3];
    const float* Wk   = (const float*)d_in[4];
    const float* bk   = (const float*)d_in[5];
    const float* Wv   = (const float*)d_in[6];
    const float* bv   = (const float*)d_in[7];
    const float* Wo   = (const float*)d_in[8];
    const float* bo   = (const float*)d_in[9];

    float* out   = (float*)d_out;
    float* probs = out + (size_t)B_ * S_ * D_;

    const size_t MD = (size_t)B_ * S_ * D_;
    __hip_bfloat16* hsb   = (__hip_bfloat16*)d_ws;
    __hip_bfloat16* wqkvb = hsb + MD;
    __hip_bfloat16* wob   = wqkvb + 3u * 1024u * 1024u;
    __hip_bfloat16* Qh    = wob + (size_t)1024 * 1024;
    __hip_bfloat16* Kh    = Qh + MD;
    __hip_bfloat16* Vt    = Kh + MD;
    __hip_bfloat16* ctxb  = Vt + MD;

    conv_kernel<<<4096, 256, 0, stream>>>(hs, hsb, (int)(MD / 4));
    conv_kernel<<<1024, 256, 0, stream>>>(Wq, wqkvb, 262144);
    conv_kernel<<<1024, 256, 0, stream>>>(Wk, wqkvb + 1048576, 262144);
    conv_kernel<<<1024, 256, 0, stream>>>(Wv, wqkvb + 2097152, 262144);
    conv_kernel<<<1024, 256, 0, stream>>>(Wo, wob, 262144);

    gemm_bt<0><<<32 * 24, 256, 0, stream>>>(hsb, wqkvb, bq, bk, bv,
                                            Qh, Kh, Vt, nullptr, 4096, 3072, 1024);

    attn_kernel<<<B_ * H_ * (S_ / 32), 512, 0, stream>>>(Qh, Kh, Vt, mask, probs, ctxb);

    gemm_bt<1><<<32 * 8, 256, 0, stream>>>(ctxb, wob, bo, nullptr, nullptr,
                                           nullptr, nullptr, nullptr, out, 4096, 1024, 1024);
}

// Round 15
// 313.728 us; speedup vs baseline: 1.1736x; 1.1736x over previous
//
#include <hip/hip_runtime.h>
#include <hip/hip_bf16.h>

#define B_ 2
#define S_ 2048
#define D_ 1024
#define H_ 16
#define HD_ 64

typedef short bf16x8 __attribute__((ext_vector_type(8)));
typedef float f32x4 __attribute__((ext_vector_type(4)));

typedef __attribute__((address_space(3))) void lds_void;
typedef const __attribute__((address_space(1))) void gbl_void;

__device__ __forceinline__ f32x4 mfma16(bf16x8 a, bf16x8 b, f32x4 c) {
    return __builtin_amdgcn_mfma_f32_16x16x32_bf16(a, b, c, 0, 0, 0);
}

__device__ __forceinline__ bf16x8 ldb8(const __hip_bfloat16* p) {
    return *reinterpret_cast<const bf16x8*>(p);
}

// ---------------- fp32 -> bf16 conversion ----------------
__global__ __launch_bounds__(256) void conv_kernel(const float* __restrict__ src,
                                                   __hip_bfloat16* __restrict__ dst, int n4) {
    int i = blockIdx.x * 256 + threadIdx.x;
    if (i >= n4) return;
    float4 f = reinterpret_cast<const float4*>(src)[i];
    union { __hip_bfloat16 h[4]; ushort4 u; } cv;
    cv.h[0] = __float2bfloat16(f.x);
    cv.h[1] = __float2bfloat16(f.y);
    cv.h[2] = __float2bfloat16(f.z);
    cv.h[3] = __float2bfloat16(f.w);
    reinterpret_cast<ushort4*>(dst)[i] = cv.u;
}

// ---------------- GEMM (m97 structure): global_load_lds w16, linear LDS ----------------
template <int MODE>
__global__ __launch_bounds__(256) void gemm_bt(
    const __hip_bfloat16* __restrict__ X, const __hip_bfloat16* __restrict__ Wt,
    const float* __restrict__ bias0, const float* __restrict__ bias1,
    const float* __restrict__ bias2,
    __hip_bfloat16* __restrict__ Yq, __hip_bfloat16* __restrict__ Yk,
    __hip_bfloat16* __restrict__ Yv, float* __restrict__ Yo,
    int M, int N, int K) {
    __shared__ __hip_bfloat16 As[128 * 32];
    __shared__ __hip_bfloat16 Bs[128 * 32];

    const int ntn = N >> 7;
    const int nwg = (M >> 7) * ntn;
    const int cpx = nwg >> 3;
    const int bid = blockIdx.x;
    const int lg = (bid & 7) * cpx + (bid >> 3);
    const int tm = lg / ntn;
    const int tn = lg % ntn;
    const int t = threadIdx.x;
    const int w = t >> 6, l = t & 63, g = l >> 4, c = l & 15;
    const int wr = w >> 1, wc = w & 1;

    const int lrow16 = l >> 2;
    const int lcol = (l & 3) * 8;

    const int r0 = w * 32 + lrow16;
    const int r1 = w * 32 + 16 + lrow16;
    const size_t xg0 = (size_t)(tm * 128 + r0) * K + lcol;
    const size_t xg1 = (size_t)(tm * 128 + r1) * K + lcol;
    const size_t wg0 = (size_t)(tn * 128 + r0) * K + lcol;
    const size_t wg1 = (size_t)(tn * 128 + r1) * K + lcol;

    f32x4 acc[4][4] = {};

    for (int k0 = 0; k0 < K; k0 += 32) {
        __syncthreads();
        __builtin_amdgcn_global_load_lds((gbl_void*)(X + xg0 + k0),
                                         (lds_void*)(As + (w * 32) * 32), 16, 0, 0);
        __builtin_amdgcn_global_load_lds((gbl_void*)(X + xg1 + k0),
                                         (lds_void*)(As + (w * 32 + 16) * 32), 16, 0, 0);
        __builtin_amdgcn_global_load_lds((gbl_void*)(Wt + wg0 + k0),
                                         (lds_void*)(Bs + (w * 32) * 32), 16, 0, 0);
        __builtin_amdgcn_global_load_lds((gbl_void*)(Wt + wg1 + k0),
                                         (lds_void*)(Bs + (w * 32 + 16) * 32), 16, 0, 0);
        __syncthreads();

        bf16x8 am[4], bn[4];
#pragma unroll
        for (int mi = 0; mi < 4; ++mi) am[mi] = ldb8(&As[(wr * 64 + mi * 16 + c) * 32 + g * 8]);
#pragma unroll
        for (int ni = 0; ni < 4; ++ni) bn[ni] = ldb8(&Bs[(wc * 64 + ni * 16 + c) * 32 + g * 8]);
#pragma unroll
        for (int mi = 0; mi < 4; ++mi)
#pragma unroll
            for (int ni = 0; ni < 4; ++ni)
                acc[mi][ni] = mfma16(am[mi], bn[ni], acc[mi][ni]);
    }

#pragma unroll
    for (int mi = 0; mi < 4; ++mi) {
        const int mbase = tm * 128 + wr * 64 + mi * 16 + g * 4;
#pragma unroll
        for (int ni = 0; ni < 4; ++ni) {
            const int n = tn * 128 + wc * 64 + ni * 16 + c;
#pragma unroll
            for (int r = 0; r < 4; ++r) {
                const int mm = mbase + r;
                float v = acc[mi][ni][r];
                if (MODE == 0) {
                    const float* bp = (n < 1024) ? bias0 : (n < 2048) ? bias1 : bias2;
                    const int nn = n & 1023;
                    v += bp[nn];
                    const int b = mm >> 11, s = mm & 2047;
                    const int h = nn >> 6, hd = nn & 63;
                    const size_t bh = (size_t)(b * H_ + h);
                    const __hip_bfloat16 bvv = __float2bfloat16(v);
                    if (n < 2048) {
                        __hip_bfloat16* dst = (n < 1024) ? Yq : Yk;
                        dst[(bh * S_ + s) * HD_ + hd] = bvv;
                    } else {
                        Yv[(bh * HD_ + hd) * S_ + s] = bvv;
                    }
                } else {
                    Yo[(size_t)mm * N + n] = v + bias0[n];
                }
            }
        }
    }
}

// K stage: byte(row*128 + (X ^ ((row&7)<<4))) = K[row][X/2]. (r11-verified)
#define STAGE_K(dstc, t8v) do {                                                   \
    const int kt_ = (t8v) * 256;                                                  \
    _Pragma("unroll")                                                             \
    for (int i_ = 0; i_ < 4; ++i_) {                                              \
        const int chunk_ = w * 4 + i_;                                            \
        const int row_ = 8 * chunk_ + (l >> 3);                                   \
        const int col_ = ((l & 7) ^ ((l >> 3) & 7)) * 8;                          \
        __builtin_amdgcn_global_load_lds(                                         \
            (gbl_void*)(Kb + (size_t)(kt_ + row_) * HD_ + col_),                  \
            (lds_void*)((dstc) + chunk_ * 1024), 16, 0, 0);                       \
    }                                                                             \
} while (0)

// V stage: byte(row*512 + (X ^ ((row&7)<<4))) = V[row][kt + X/2]. (r11-verified)
#define STAGE_V(dstc, t8v) do {                                                   \
    const int kt_ = (t8v) * 256;                                                  \
    _Pragma("unroll")                                                             \
    for (int i_ = 0; i_ < 4; ++i_) {                                              \
        const int chunk_ = w * 4 + i_;                                            \
        const int row_ = 2 * chunk_ + (l >> 5);                                   \
        const int col_ = ((l & 31) ^ (row_ & 7)) * 8;                             \
        __builtin_amdgcn_global_load_lds(                                         \
            (gbl_void*)(Vb + (size_t)row_ * S_ + kt_ + col_),                     \
            (lds_void*)((dstc) + chunk_ * 1024), 16, 0, 0);                       \
    }                                                                             \
} while (0)

// ---------------- fused attention: r11 pipeline, SINGLE q-group (low VGPR) ----------------
// 4096 blocks x 8 waves; block owns 16 q-rows; wave w owns k-window [32w,32w+32)
// per 256-k tile. VGPR ~100 (uA 32 + aq 8 + cacc 16) -> 2 blocks/CU resident,
// giving cross-block overlap of barrier/latency stalls that r11's 1-block/CU
// dual-group version could not hide.
__global__ __launch_bounds__(512, 4) void attn_kernel(
    const __hip_bfloat16* __restrict__ Qh, const __hip_bfloat16* __restrict__ Kh,
    const __hip_bfloat16* __restrict__ Vt, const float* __restrict__ mask,
    float* __restrict__ probs, __hip_bfloat16* __restrict__ ctx) {
    union SMem {
        char Kdb[2][32768];      // K/V tile double-buffer (64 KB)
        float Cred[8][16][68];   // epilogue reduce (aliases)
    };
    __shared__ SMem sm;
    __shared__ float msk[2048];
    __shared__ float sred[8][16];
    __shared__ float invsh[16];

    const int bid = blockIdx.x;
    const int lg = (bid & 7) * 512 + (bid >> 3);   // 4096 blocks, bijective XCD swizzle
    const int qt = lg & 127;                        // S/16
    const int bh = lg >> 7;
    const int b = bh >> 4, h = bh & 15;
    const int t = threadIdx.x;
    const int w = t >> 6, l = t & 63, g = l >> 4, c = l & 15;
    const int q0 = qt * 16;
    const int kw = 32 * w;

    const __hip_bfloat16* Qb = Qh + (size_t)bh * S_ * HD_;
    const __hip_bfloat16* Kb = Kh + (size_t)bh * S_ * HD_;
    const __hip_bfloat16* Vb = Vt + (size_t)bh * HD_ * S_;
    const float* mrow = mask + (size_t)b * S_;

    *reinterpret_cast<float4*>(&msk[t * 4]) =
        *reinterpret_cast<const float4*>(&mrow[t * 4]);

    const bf16x8 aq0 = ldb8(&Qb[(q0 + c) * HD_ + g * 8]);
    const bf16x8 aq1 = ldb8(&Qb[(q0 + c) * HD_ + 32 + g * 8]);

    unsigned int uA[8][2][2];
    float lsum = 0.f;

    // ---- pass 1: pipelined K tiles, QK^T + exp, P~ -> regs ----
    STAGE_K(sm.Kdb[0], 0);
#pragma unroll
    for (int t8 = 0; t8 < 8; ++t8) {
        char* cur = sm.Kdb[t8 & 1];
        if (t8 < 7) {
            STAGE_K(sm.Kdb[(t8 & 1) ^ 1], t8 + 1);
            asm volatile("s_waitcnt vmcnt(4)" ::: "memory");
        } else {
            asm volatile("s_waitcnt vmcnt(0)" ::: "memory");
        }
        if (t8 == 0) asm volatile("s_waitcnt lgkmcnt(0)" ::: "memory");
        __builtin_amdgcn_s_barrier();
        __builtin_amdgcn_sched_barrier(0);
        const int kt = t8 * 256;
#pragma unroll
        for (int ss = 0; ss < 2; ++ss) {
            const int krow = kw + ss * 16 + c;
            const char* kb2 = cur + krow * 128;
            const int sw = (krow & 7) << 4;
            const bf16x8 k0 = *reinterpret_cast<const bf16x8*>(kb2 + ((g * 16) ^ sw));
            const bf16x8 k1 = *reinterpret_cast<const bf16x8*>(kb2 + ((64 + g * 16) ^ sw));
            f32x4 aA = {};
            aA = mfma16(k0, aq0, aA);
            aA = mfma16(k1, aq1, aA);
            const float4 mk = *reinterpret_cast<const float4*>(&msk[kt + kw + ss * 16 + g * 4]);
            const float p0 = __expf(aA[0] * 0.125f + mk.x);
            const float p1 = __expf(aA[1] * 0.125f + mk.y);
            const float p2 = __expf(aA[2] * 0.125f + mk.z);
            const float p3 = __expf(aA[3] * 0.125f + mk.w);
            lsum += (p0 + p1) + (p2 + p3);
            union { __hip_bfloat16 hh[2]; unsigned int ui; } w0, w1;
            w0.hh[0] = __float2bfloat16(p0); w0.hh[1] = __float2bfloat16(p1);
            w1.hh[0] = __float2bfloat16(p2); w1.hh[1] = __float2bfloat16(p3);
            uA[t8][ss][0] = w0.ui; uA[t8][ss][1] = w1.ui;
        }
        __builtin_amdgcn_sched_barrier(0);
        __builtin_amdgcn_s_barrier();
    }

    // ---- denominator reduce ----
    lsum += __shfl_xor(lsum, 16);
    lsum += __shfl_xor(lsum, 32);
    if (g == 0) sred[w][c] = lsum;
    __syncthreads();
    float tot = 0.f;
#pragma unroll
    for (int w8 = 0; w8 < 8; ++w8) tot += sred[w8][c];
    const float invA = 1.0f / tot;
    if (w == 0 && g == 0) invsh[c] = invA;

    // ---- pass 2: pipelined V tiles, probs stores interleaved, PV ----
    f32x4 cacc[4] = {};
    float* prowA = probs + ((size_t)bh * S_ + q0 + c) * S_;
    const int src0 = 32 * (g & 1) + c;
    const int src1 = src0 + 16;
    const int sigma = g >> 1;
    STAGE_V(sm.Kdb[0], 0);
#pragma unroll
    for (int t8 = 0; t8 < 8; ++t8) {
        const char* cur = sm.Kdb[t8 & 1];
        if (t8 < 7) STAGE_V(sm.Kdb[(t8 & 1) ^ 1], t8 + 1);
        // queue: [S(t-2)(2)], L(t)(4), [S(t-1)(2)], [L(t+1)(4)] -> retire thru L(t)
        if (t8 == 0)      asm volatile("s_waitcnt vmcnt(4)" ::: "memory");
        else if (t8 == 7) asm volatile("s_waitcnt vmcnt(2)" ::: "memory");
        else              asm volatile("s_waitcnt vmcnt(6)" ::: "memory");
        __builtin_amdgcn_s_barrier();
        __builtin_amdgcn_sched_barrier(0);
        const int kt = t8 * 256;
#pragma unroll
        for (int ss = 0; ss < 2; ++ss) {
            f32x4 oA;
            oA[0] = __uint_as_float(uA[t8][ss][0] << 16) * invA;
            oA[1] = __uint_as_float(uA[t8][ss][0] & 0xffff0000u) * invA;
            oA[2] = __uint_as_float(uA[t8][ss][1] << 16) * invA;
            oA[3] = __uint_as_float(uA[t8][ss][1] & 0xffff0000u) * invA;
            *reinterpret_cast<f32x4*>(&prowA[kt + kw + ss * 16 + g * 4]) = oA;
        }
        union { unsigned int ui[4]; bf16x8 v; } afA;
        {
            const unsigned int x00 = __shfl(uA[t8][0][0], src0);
            const unsigned int x10 = __shfl(uA[t8][1][0], src0);
            const unsigned int x01 = __shfl(uA[t8][0][1], src0);
            const unsigned int x11 = __shfl(uA[t8][1][1], src0);
            const unsigned int x02 = __shfl(uA[t8][0][0], src1);
            const unsigned int x12 = __shfl(uA[t8][1][0], src1);
            const unsigned int x03 = __shfl(uA[t8][0][1], src1);
            const unsigned int x13 = __shfl(uA[t8][1][1], src1);
            afA.ui[0] = sigma ? x10 : x00;
            afA.ui[1] = sigma ? x11 : x01;
            afA.ui[2] = sigma ? x12 : x02;
            afA.ui[3] = sigma ? x13 : x03;
        }
#pragma unroll
        for (int n = 0; n < 4; ++n) {
            const int vrow = n * 16 + c;
            const bf16x8 bv = *reinterpret_cast<const bf16x8*>(
                cur + vrow * 512 + ((64 * w + g * 16) ^ ((vrow & 7) << 4)));
            cacc[n] = mfma16(afA.v, bv, cacc[n]);
        }
        __builtin_amdgcn_sched_barrier(0);
        __builtin_amdgcn_s_barrier();
    }

    // ---- cross-wave PV reduce ----
    __syncthreads();
#pragma unroll
    for (int n = 0; n < 4; ++n)
#pragma unroll
        for (int r = 0; r < 4; ++r)
            sm.Cred[w][g * 4 + r][n * 16 + c] = cacc[n][r];
    __syncthreads();
    {
        const int row = t >> 5, col2 = (t & 31) * 2;
        float a0 = 0.f, a1 = 0.f;
#pragma unroll
        for (int w8 = 0; w8 < 8; ++w8) {
            const float2 vv = *reinterpret_cast<const float2*>(&sm.Cred[w8][row][col2]);
            a0 += vv.x; a1 += vv.y;
        }
        const float fin = invsh[row];
        union { __hip_bfloat16 hh[2]; unsigned int ui; } ov;
        ov.hh[0] = __float2bfloat16(a0 * fin);
        ov.hh[1] = __float2bfloat16(a1 * fin);
        *reinterpret_cast<unsigned int*>(
            &ctx[((size_t)b * S_ + q0 + row) * D_ + h * HD_ + col2]) = ov.ui;
    }
}

// ---------------- launch ----------------
extern "C" void kernel_launch(void* const* d_in, const int* in_sizes, int n_in,
                              void* d_out, int out_size, void* d_ws, size_t ws_size,
                              hipStream_t stream) {
    const float* hs   = (const float*)d_in[0];
    const float* mask = (const float*)d_in[1];
    const float* Wq   = (const float*)d_in[2];
    const float* bq   = (const float*)d_in[3];
    const float* Wk   = (const float*)d_in[4];
    const float* bk   = (const float*)d_in[5];
    const float* Wv   = (const float*)d_in[6];
    const float* bv   = (const float*)d_in[7];
    const float* Wo   = (const float*)d_in[8];
    const float* bo   = (const float*)d_in[9];

    float* out   = (float*)d_out;
    float* probs = out + (size_t)B_ * S_ * D_;

    const size_t MD = (size_t)B_ * S_ * D_;
    __hip_bfloat16* hsb   = (__hip_bfloat16*)d_ws;
    __hip_bfloat16* wqkvb = hsb + MD;
    __hip_bfloat16* wob   = wqkvb + 3u * 1024u * 1024u;
    __hip_bfloat16* Qh    = wob + (size_t)1024 * 1024;
    __hip_bfloat16* Kh    = Qh + MD;
    __hip_bfloat16* Vt    = Kh + MD;
    __hip_bfloat16* ctxb  = Vt + MD;

    conv_kernel<<<4096, 256, 0, stream>>>(hs, hsb, (int)(MD / 4));
    conv_kernel<<<1024, 256, 0, stream>>>(Wq, wqkvb, 262144);
    conv_kernel<<<1024, 256, 0, stream>>>(Wk, wqkvb + 1048576, 262144);
    conv_kernel<<<1024, 256, 0, stream>>>(Wv, wqkvb + 2097152, 262144);
    conv_kernel<<<1024, 256, 0, stream>>>(Wo, wob, 262144);

    gemm_bt<0><<<32 * 24, 256, 0, stream>>>(hsb, wqkvb, bq, bk, bv,
                                            Qh, Kh, Vt, nullptr, 4096, 3072, 1024);

    attn_kernel<<<B_ * H_ * (S_ / 16), 512, 0, stream>>>(Qh, Kh, Vt, mask, probs, ctxb);

    gemm_bt<1><<<32 * 8, 256, 0, stream>>>(ctxb, wob, bo, nullptr, nullptr,
                                           nullptr, nullptr, nullptr, out, 4096, 1024, 1024);
}

// Round 17
// 309.404 us; speedup vs baseline: 1.1900x; 1.0140x over previous
//
#include <hip/hip_runtime.h>
#include <hip/hip_bf16.h>

#define B_ 2
#define S_ 2048
#define D_ 1024
#define H_ 16
#define HD_ 64

typedef short bf16x8 __attribute__((ext_vector_type(8)));
typedef float f32x4 __attribute__((ext_vector_type(4)));

typedef __attribute__((address_space(3))) void lds_void;
typedef const __attribute__((address_space(1))) void gbl_void;

__device__ __forceinline__ f32x4 mfma16(bf16x8 a, bf16x8 b, f32x4 c) {
    return __builtin_amdgcn_mfma_f32_16x16x32_bf16(a, b, c, 0, 0, 0);
}

__device__ __forceinline__ bf16x8 ldb8(const __hip_bfloat16* p) {
    return *reinterpret_cast<const bf16x8*>(p);
}

// ---------------- fp32 -> bf16 conversion ----------------
__global__ __launch_bounds__(256) void conv_kernel(const float* __restrict__ src,
                                                   __hip_bfloat16* __restrict__ dst, int n4) {
    int i = blockIdx.x * 256 + threadIdx.x;
    if (i >= n4) return;
    float4 f = reinterpret_cast<const float4*>(src)[i];
    union { __hip_bfloat16 h[4]; ushort4 u; } cv;
    cv.h[0] = __float2bfloat16(f.x);
    cv.h[1] = __float2bfloat16(f.y);
    cv.h[2] = __float2bfloat16(f.z);
    cv.h[3] = __float2bfloat16(f.w);
    reinterpret_cast<ushort4*>(dst)[i] = cv.u;
}

// ---------------- GEMM (m97 structure): global_load_lds w16, linear LDS ----------------
template <int MODE>
__global__ __launch_bounds__(256) void gemm_bt(
    const __hip_bfloat16* __restrict__ X, const __hip_bfloat16* __restrict__ Wt,
    const float* __restrict__ bias0, const float* __restrict__ bias1,
    const float* __restrict__ bias2,
    __hip_bfloat16* __restrict__ Yq, __hip_bfloat16* __restrict__ Yk,
    __hip_bfloat16* __restrict__ Yv, float* __restrict__ Yo,
    int M, int N, int K) {
    __shared__ __hip_bfloat16 As[128 * 32];
    __shared__ __hip_bfloat16 Bs[128 * 32];

    const int ntn = N >> 7;
    const int nwg = (M >> 7) * ntn;
    const int cpx = nwg >> 3;
    const int bid = blockIdx.x;
    const int lg = (bid & 7) * cpx + (bid >> 3);
    const int tm = lg / ntn;
    const int tn = lg % ntn;
    const int t = threadIdx.x;
    const int w = t >> 6, l = t & 63, g = l >> 4, c = l & 15;
    const int wr = w >> 1, wc = w & 1;

    const int lrow16 = l >> 2;
    const int lcol = (l & 3) * 8;

    const int r0 = w * 32 + lrow16;
    const int r1 = w * 32 + 16 + lrow16;
    const size_t xg0 = (size_t)(tm * 128 + r0) * K + lcol;
    const size_t xg1 = (size_t)(tm * 128 + r1) * K + lcol;
    const size_t wg0 = (size_t)(tn * 128 + r0) * K + lcol;
    const size_t wg1 = (size_t)(tn * 128 + r1) * K + lcol;

    f32x4 acc[4][4] = {};

    for (int k0 = 0; k0 < K; k0 += 32) {
        __syncthreads();
        __builtin_amdgcn_global_load_lds((gbl_void*)(X + xg0 + k0),
                                         (lds_void*)(As + (w * 32) * 32), 16, 0, 0);
        __builtin_amdgcn_global_load_lds((gbl_void*)(X + xg1 + k0),
                                         (lds_void*)(As + (w * 32 + 16) * 32), 16, 0, 0);
        __builtin_amdgcn_global_load_lds((gbl_void*)(Wt + wg0 + k0),
                                         (lds_void*)(Bs + (w * 32) * 32), 16, 0, 0);
        __builtin_amdgcn_global_load_lds((gbl_void*)(Wt + wg1 + k0),
                                         (lds_void*)(Bs + (w * 32 + 16) * 32), 16, 0, 0);
        __syncthreads();

        bf16x8 am[4], bn[4];
#pragma unroll
        for (int mi = 0; mi < 4; ++mi) am[mi] = ldb8(&As[(wr * 64 + mi * 16 + c) * 32 + g * 8]);
#pragma unroll
        for (int ni = 0; ni < 4; ++ni) bn[ni] = ldb8(&Bs[(wc * 64 + ni * 16 + c) * 32 + g * 8]);
#pragma unroll
        for (int mi = 0; mi < 4; ++mi)
#pragma unroll
            for (int ni = 0; ni < 4; ++ni)
                acc[mi][ni] = mfma16(am[mi], bn[ni], acc[mi][ni]);
    }

#pragma unroll
    for (int mi = 0; mi < 4; ++mi) {
        const int mbase = tm * 128 + wr * 64 + mi * 16 + g * 4;
#pragma unroll
        for (int ni = 0; ni < 4; ++ni) {
            const int n = tn * 128 + wc * 64 + ni * 16 + c;
#pragma unroll
            for (int r = 0; r < 4; ++r) {
                const int mm = mbase + r;
                float v = acc[mi][ni][r];
                if (MODE == 0) {
                    const float* bp = (n < 1024) ? bias0 : (n < 2048) ? bias1 : bias2;
                    const int nn = n & 1023;
                    v += bp[nn];
                    const int b = mm >> 11, s = mm & 2047;
                    const int h = nn >> 6, hd = nn & 63;
                    const size_t bh = (size_t)(b * H_ + h);
                    const __hip_bfloat16 bvv = __float2bfloat16(v);
                    if (n < 2048) {
                        __hip_bfloat16* dst = (n < 1024) ? Yq : Yk;
                        dst[(bh * S_ + s) * HD_ + hd] = bvv;
                    } else {
                        Yv[(bh * HD_ + hd) * S_ + s] = bvv;
                    }
                } else {
                    Yo[(size_t)mm * N + n] = v + bias0[n];
                }
            }
        }
    }
}

// K stage (wave-private): wave w stages rows [32w,32w+32) = exactly its read
// window. byte(row*128 + (X ^ ((row&7)<<4))) = K[row][X/2].
#define STAGE_K(dstc, t8v) do {                                                   \
    const int kt_ = (t8v) * 256;                                                  \
    _Pragma("unroll")                                                             \
    for (int i_ = 0; i_ < 4; ++i_) {                                              \
        const int chunk_ = w * 4 + i_;                                            \
        const int row_ = 8 * chunk_ + (l >> 3);                                   \
        const int col_ = ((l & 7) ^ ((l >> 3) & 7)) * 8;                          \
        __builtin_amdgcn_global_load_lds(                                         \
            (gbl_void*)(Kb + (size_t)(kt_ + row_) * HD_ + col_),                  \
            (lds_void*)((dstc) + chunk_ * 1024), 16, 0, 0);                       \
    }                                                                             \
} while (0)

// V stage (wave-private): wave w stages ALL 64 hd-rows x its 32-k (64B) window
// into its own 4KB slice, layout [64 rows][64B], slot s holds source byte
// s ^ ((row&3)<<4) of the window (read-side applies same XOR).
#define STAGE_VP(dstc, t8v) do {                                                  \
    const int kb_ = ((t8v) * 256 + 32 * w) * 2;                                   \
    _Pragma("unroll")                                                             \
    for (int i_ = 0; i_ < 4; ++i_) {                                              \
        const int row_ = 16 * i_ + (l >> 2);                                      \
        const int scol_ = ((l & 3) * 16) ^ ((row_ & 3) << 4);                     \
        __builtin_amdgcn_global_load_lds(                                         \
            (gbl_void*)((const char*)Vb + (size_t)row_ * (S_ * 2) + kb_ + scol_), \
            (lds_void*)((dstc) + w * 4096 + i_ * 1024), 16, 0, 0);                \
    }                                                                             \
} while (0)

// ---------------- fused attention: ZERO hot-loop barriers ----------------
// 4096 blocks x 8 waves; block owns 16 q-rows; wave w owns k-window [32w,32w+32)
// per 256-k tile. K AND V staging are wave-private -> each wave runs a private
// vmcnt-only double-buffered pipeline; no s_barrier in either pass. Sync only
// at msk init, the denominator seam, and the ctx epilogue.
// Pass-2 vmcnt (4 loads + 2 stores per tile): queue into iter-t wait is
// [loads(t)(4), stores(t-1)(2), loads(t+1)(4)] -> body vmcnt(6); t=0: (4); t=7: (2).
__global__ __launch_bounds__(512, 4) void attn_kernel(
    const __hip_bfloat16* __restrict__ Qh, const __hip_bfloat16* __restrict__ Kh,
    const __hip_bfloat16* __restrict__ Vt, const float* __restrict__ mask,
    float* __restrict__ probs, __hip_bfloat16* __restrict__ ctx) {
    union SMem {
        char KV[2][32768];       // per-wave 4KB slices x 8 waves, double-buffered
        float Cred[8][16][68];   // epilogue reduce (aliases)
    };
    __shared__ SMem sm;
    __shared__ float msk[2048];
    __shared__ float sred[8][16];
    __shared__ float invsh[16];

    const int bid = blockIdx.x;
    const int lg = (bid & 7) * 512 + (bid >> 3);   // bijective XCD swizzle
    const int qt = lg & 127;                        // S/16
    const int bh = lg >> 7;
    const int b = bh >> 4, h = bh & 15;
    const int t = threadIdx.x;
    const int w = t >> 6, l = t & 63, g = l >> 4, c = l & 15;
    const int q0 = qt * 16;
    const int kw = 32 * w;

    const __hip_bfloat16* Qb = Qh + (size_t)bh * S_ * HD_;
    const __hip_bfloat16* Kb = Kh + (size_t)bh * S_ * HD_;
    const __hip_bfloat16* Vb = Vt + (size_t)bh * HD_ * S_;
    const float* mrow = mask + (size_t)b * S_;

    *reinterpret_cast<float4*>(&msk[t * 4]) =
        *reinterpret_cast<const float4*>(&mrow[t * 4]);

    const bf16x8 aq0 = ldb8(&Qb[(q0 + c) * HD_ + g * 8]);
    const bf16x8 aq1 = ldb8(&Qb[(q0 + c) * HD_ + 32 + g * 8]);

    __syncthreads();   // msk visible; vmcnt queue drained -> exact counting

    unsigned int uA[8][2][2];
    float lsum = 0.f;

    // ---- pass 1: per-wave pipelined K tiles, NO barriers ----
    STAGE_K(sm.KV[0], 0);
#pragma unroll
    for (int t8 = 0; t8 < 8; ++t8) {
        const char* cur = sm.KV[t8 & 1];
        if (t8 < 7) {
            STAGE_K(sm.KV[(t8 & 1) ^ 1], t8 + 1);
            asm volatile("s_waitcnt vmcnt(4)" ::: "memory");
        } else {
            asm volatile("s_waitcnt vmcnt(0)" ::: "memory");
        }
        __builtin_amdgcn_sched_barrier(0);
        const int kt = t8 * 256;
#pragma unroll
        for (int ss = 0; ss < 2; ++ss) {
            const int krow = kw + ss * 16 + c;
            const char* kb2 = cur + krow * 128;
            const int sw = (krow & 7) << 4;
            const bf16x8 k0 = *reinterpret_cast<const bf16x8*>(kb2 + ((g * 16) ^ sw));
            const bf16x8 k1 = *reinterpret_cast<const bf16x8*>(kb2 + ((64 + g * 16) ^ sw));
            f32x4 aA = {};
            aA = mfma16(k0, aq0, aA);
            aA = mfma16(k1, aq1, aA);
            const float4 mk = *reinterpret_cast<const float4*>(&msk[kt + kw + ss * 16 + g * 4]);
            const float p0 = __expf(aA[0] * 0.125f + mk.x);
            const float p1 = __expf(aA[1] * 0.125f + mk.y);
            const float p2 = __expf(aA[2] * 0.125f + mk.z);
            const float p3 = __expf(aA[3] * 0.125f + mk.w);
            lsum += (p0 + p1) + (p2 + p3);
            union { __hip_bfloat16 hh[2]; unsigned int ui; } w0, w1;
            w0.hh[0] = __float2bfloat16(p0); w0.hh[1] = __float2bfloat16(p1);
            w1.hh[0] = __float2bfloat16(p2); w1.hh[1] = __float2bfloat16(p3);
            uA[t8][ss][0] = w0.ui; uA[t8][ss][1] = w1.ui;
        }
        __builtin_amdgcn_sched_barrier(0);
    }

    // ---- denominator seam (raw barrier; vmcnt queue empty after pass 1) ----
    lsum += __shfl_xor(lsum, 16);
    lsum += __shfl_xor(lsum, 32);
    if (g == 0) sred[w][c] = lsum;
    asm volatile("s_waitcnt lgkmcnt(0)" ::: "memory");
    __builtin_amdgcn_s_barrier();
    __builtin_amdgcn_sched_barrier(0);
    float tot = 0.f;
#pragma unroll
    for (int w8 = 0; w8 < 8; ++w8) tot += sred[w8][c];
    const float invA = 1.0f / tot;
    if (w == 0 && g == 0) invsh[c] = invA;

    // ---- pass 2: per-wave pipelined V tiles + probs stores, NO barriers ----
    f32x4 cacc[4] = {};
    float* prowA = probs + ((size_t)bh * S_ + q0 + c) * S_;
    const int src0 = 32 * (g & 1) + c;
    const int src1 = src0 + 16;
    const int sigma = g >> 1;
    STAGE_VP(sm.KV[0], 0);
#pragma unroll
    for (int t8 = 0; t8 < 8; ++t8) {
        const char* curV = sm.KV[t8 & 1] + w * 4096;
        if (t8 < 7) STAGE_VP(sm.KV[(t8 & 1) ^ 1], t8 + 1);
        // correct counted waits: loads(t) must land; ops-after = stores(t-1)(2)+loads(t+1)(4)
        if (t8 == 0)      asm volatile("s_waitcnt vmcnt(4)" ::: "memory");
        else if (t8 == 7) asm volatile("s_waitcnt vmcnt(2)" ::: "memory");
        else              asm volatile("s_waitcnt vmcnt(6)" ::: "memory");
        __builtin_amdgcn_sched_barrier(0);
        const int kt = t8 * 256;
#pragma unroll
        for (int ss = 0; ss < 2; ++ss) {
            f32x4 oA;
            oA[0] = __uint_as_float(uA[t8][ss][0] << 16) * invA;
            oA[1] = __uint_as_float(uA[t8][ss][0] & 0xffff0000u) * invA;
            oA[2] = __uint_as_float(uA[t8][ss][1] << 16) * invA;
            oA[3] = __uint_as_float(uA[t8][ss][1] & 0xffff0000u) * invA;
            *reinterpret_cast<f32x4*>(&prowA[kt + kw + ss * 16 + g * 4]) = oA;
        }
        union { unsigned int ui[4]; bf16x8 v; } afA;
        {
            const unsigned int x00 = __shfl(uA[t8][0][0], src0);
            const unsigned int x10 = __shfl(uA[t8][1][0], src0);
            const unsigned int x01 = __shfl(uA[t8][0][1], src0);
            const unsigned int x11 = __shfl(uA[t8][1][1], src0);
            const unsigned int x02 = __shfl(uA[t8][0][0], src1);
            const unsigned int x12 = __shfl(uA[t8][1][0], src1);
            const unsigned int x03 = __shfl(uA[t8][0][1], src1);
            const unsigned int x13 = __shfl(uA[t8][1][1], src1);
            afA.ui[0] = sigma ? x10 : x00;
            afA.ui[1] = sigma ? x11 : x01;
            afA.ui[2] = sigma ? x12 : x02;
            afA.ui[3] = sigma ? x13 : x03;
        }
#pragma unroll
        for (int n = 0; n < 4; ++n) {
            const int vrow = n * 16 + c;
            const bf16x8 bv = *reinterpret_cast<const bf16x8*>(
                curV + vrow * 64 + ((g * 16) ^ ((vrow & 3) << 4)));
            cacc[n] = mfma16(afA.v, bv, cacc[n]);
        }
        __builtin_amdgcn_sched_barrier(0);
    }

    // ---- cross-wave PV reduce (Cred aliases KV; full drain first) ----
    __syncthreads();
#pragma unroll
    for (int n = 0; n < 4; ++n)
#pragma unroll
        for (int r = 0; r < 4; ++r)
            sm.Cred[w][g * 4 + r][n * 16 + c] = cacc[n][r];
    __syncthreads();
    {
        const int row = t >> 5, col2 = (t & 31) * 2;
        float a0 = 0.f, a1 = 0.f;
#pragma unroll
        for (int w8 = 0; w8 < 8; ++w8) {
            const float2 vv = *reinterpret_cast<const float2*>(&sm.Cred[w8][row][col2]);
            a0 += vv.x; a1 += vv.y;
        }
        const float fin = invsh[row];
        union { __hip_bfloat16 hh[2]; unsigned int ui; } ov;
        ov.hh[0] = __float2bfloat16(a0 * fin);
        ov.hh[1] = __float2bfloat16(a1 * fin);
        *reinterpret_cast<unsigned int*>(
            &ctx[((size_t)b * S_ + q0 + row) * D_ + h * HD_ + col2]) = ov.ui;
    }
}

// ---------------- launch ----------------
extern "C" void kernel_launch(void* const* d_in, const int* in_sizes, int n_in,
                              void* d_out, int out_size, void* d_ws, size_t ws_size,
                              hipStream_t stream) {
    const float* hs   = (const float*)d_in[0];
    const float* mask = (const float*)d_in[1];
    const float* Wq   = (const float*)d_in[2];
    const float* bq   = (const float*)d_in[3];
    const float* Wk   = (const float*)d_in[4];
    const float* bk   = (const float*)d_in[5];
    const float* Wv   = (const float*)d_in[6];
    const float* bv   = (const float*)d_in[7];
    const float* Wo   = (const float*)d_in[8];
    const float* bo   = (const float*)d_in[9];

    float* out   = (float*)d_out;
    float* probs = out + (size_t)B_ * S_ * D_;

    const size_t MD = (size_t)B_ * S_ * D_;
    __hip_bfloat16* hsb   = (__hip_bfloat16*)d_ws;
    __hip_bfloat16* wqkvb = hsb + MD;
    __hip_bfloat16* wob   = wqkvb + 3u * 1024u * 1024u;
    __hip_bfloat16* Qh    = wob + (size_t)1024 * 1024;
    __hip_bfloat16* Kh    = Qh + MD;
    __hip_bfloat16* Vt    = Kh + MD;
    __hip_bfloat16* ctxb  = Vt + MD;

    conv_kernel<<<4096, 256, 0, stream>>>(hs, hsb, (int)(MD / 4));
    conv_kernel<<<1024, 256, 0, stream>>>(Wq, wqkvb, 262144);
    conv_kernel<<<1024, 256, 0, stream>>>(Wk, wqkvb + 1048576, 262144);
    conv_kernel<<<1024, 256, 0, stream>>>(Wv, wqkvb + 2097152, 262144);
    conv_kernel<<<1024, 256, 0, stream>>>(Wo, wob, 262144);

    gemm_bt<0><<<32 * 24, 256, 0, stream>>>(hsb, wqkvb, bq, bk, bv,
                                            Qh, Kh, Vt, nullptr, 4096, 3072, 1024);

    attn_kernel<<<B_ * H_ * (S_ / 16), 512, 0, stream>>>(Qh, Kh, Vt, mask, probs, ctxb);

    gemm_bt<1><<<32 * 8, 256, 0, stream>>>(ctxb, wob, bo, nullptr, nullptr,
                                           nullptr, nullptr, nullptr, out, 4096, 1024, 1024);
}

// Round 18
// 272.862 us; speedup vs baseline: 1.3494x; 1.1339x over previous
//
#include <hip/hip_runtime.h>
#include <hip/hip_bf16.h>

#define B_ 2
#define S_ 2048
#define D_ 1024
#define H_ 16
#define HD_ 64

typedef short bf16x8 __attribute__((ext_vector_type(8)));
typedef float f32x4 __attribute__((ext_vector_type(4)));

typedef __attribute__((address_space(3))) void lds_void;
typedef const __attribute__((address_space(1))) void gbl_void;

__device__ __forceinline__ f32x4 mfma16(bf16x8 a, bf16x8 b, f32x4 c) {
    return __builtin_amdgcn_mfma_f32_16x16x32_bf16(a, b, c, 0, 0, 0);
}

__device__ __forceinline__ bf16x8 ldb8(const __hip_bfloat16* p) {
    return *reinterpret_cast<const bf16x8*>(p);
}

// ---------------- fused fp32 -> bf16 conversion (ALL tensors, one launch) ----------------
// i in [0, 1M): hs (1M float4). i in [1M, 2M): weights, 256K float4 each:
// r = (i-1M)>>18 selects Wq/Wk/Wv/Wo.
__global__ __launch_bounds__(256) void conv_all(
    const float* __restrict__ hs, const float* __restrict__ Wq,
    const float* __restrict__ Wk, const float* __restrict__ Wv,
    const float* __restrict__ Wo,
    __hip_bfloat16* __restrict__ hsb, __hip_bfloat16* __restrict__ wqkvb,
    __hip_bfloat16* __restrict__ wob) {
    const int i = blockIdx.x * 256 + threadIdx.x;
    const float* src;
    __hip_bfloat16* dst;
    int off;
    if (i < (1 << 20)) {
        src = hs; dst = hsb; off = i;
    } else {
        const int j = i - (1 << 20);
        const int r = j >> 18;             // 262144 float4 per weight
        off = j & 0x3ffff;
        src = (r == 0) ? Wq : (r == 1) ? Wk : (r == 2) ? Wv : Wo;
        dst = (r < 3) ? wqkvb + (size_t)r * 1048576 : wob;
    }
    float4 f = reinterpret_cast<const float4*>(src)[off];
    union { __hip_bfloat16 h[4]; ushort4 u; } cv;
    cv.h[0] = __float2bfloat16(f.x);
    cv.h[1] = __float2bfloat16(f.y);
    cv.h[2] = __float2bfloat16(f.z);
    cv.h[3] = __float2bfloat16(f.w);
    reinterpret_cast<ushort4*>(dst)[off] = cv.u;
}

// ---------------- GEMM (m97 structure): global_load_lds w16, linear LDS ----------------
// MODE 0 epilogue: Vt path vectorized (4 consecutive s -> one ushort4 store).
template <int MODE>
__global__ __launch_bounds__(256) void gemm_bt(
    const __hip_bfloat16* __restrict__ X, const __hip_bfloat16* __restrict__ Wt,
    const float* __restrict__ bias0, const float* __restrict__ bias1,
    const float* __restrict__ bias2,
    __hip_bfloat16* __restrict__ Yq, __hip_bfloat16* __restrict__ Yk,
    __hip_bfloat16* __restrict__ Yv, float* __restrict__ Yo,
    int M, int N, int K) {
    __shared__ __hip_bfloat16 As[128 * 32];
    __shared__ __hip_bfloat16 Bs[128 * 32];

    const int ntn = N >> 7;
    const int nwg = (M >> 7) * ntn;
    const int cpx = nwg >> 3;
    const int bid = blockIdx.x;
    const int lg = (bid & 7) * cpx + (bid >> 3);
    const int tm = lg / ntn;
    const int tn = lg % ntn;
    const int t = threadIdx.x;
    const int w = t >> 6, l = t & 63, g = l >> 4, c = l & 15;
    const int wr = w >> 1, wc = w & 1;

    const int lrow16 = l >> 2;
    const int lcol = (l & 3) * 8;

    const int r0 = w * 32 + lrow16;
    const int r1 = w * 32 + 16 + lrow16;
    const size_t xg0 = (size_t)(tm * 128 + r0) * K + lcol;
    const size_t xg1 = (size_t)(tm * 128 + r1) * K + lcol;
    const size_t wg0 = (size_t)(tn * 128 + r0) * K + lcol;
    const size_t wg1 = (size_t)(tn * 128 + r1) * K + lcol;

    f32x4 acc[4][4] = {};

    for (int k0 = 0; k0 < K; k0 += 32) {
        __syncthreads();
        __builtin_amdgcn_global_load_lds((gbl_void*)(X + xg0 + k0),
                                         (lds_void*)(As + (w * 32) * 32), 16, 0, 0);
        __builtin_amdgcn_global_load_lds((gbl_void*)(X + xg1 + k0),
                                         (lds_void*)(As + (w * 32 + 16) * 32), 16, 0, 0);
        __builtin_amdgcn_global_load_lds((gbl_void*)(Wt + wg0 + k0),
                                         (lds_void*)(Bs + (w * 32) * 32), 16, 0, 0);
        __builtin_amdgcn_global_load_lds((gbl_void*)(Wt + wg1 + k0),
                                         (lds_void*)(Bs + (w * 32 + 16) * 32), 16, 0, 0);
        __syncthreads();

        bf16x8 am[4], bn[4];
#pragma unroll
        for (int mi = 0; mi < 4; ++mi) am[mi] = ldb8(&As[(wr * 64 + mi * 16 + c) * 32 + g * 8]);
#pragma unroll
        for (int ni = 0; ni < 4; ++ni) bn[ni] = ldb8(&Bs[(wc * 64 + ni * 16 + c) * 32 + g * 8]);
#pragma unroll
        for (int mi = 0; mi < 4; ++mi)
#pragma unroll
            for (int ni = 0; ni < 4; ++ni)
                acc[mi][ni] = mfma16(am[mi], bn[ni], acc[mi][ni]);
    }

#pragma unroll
    for (int mi = 0; mi < 4; ++mi) {
        const int mbase = tm * 128 + wr * 64 + mi * 16 + g * 4;
#pragma unroll
        for (int ni = 0; ni < 4; ++ni) {
            const int n = tn * 128 + wc * 64 + ni * 16 + c;
            if (MODE == 0) {
                const float* bp = (n < 1024) ? bias0 : (n < 2048) ? bias1 : bias2;
                const int nn = n & 1023;
                const float bias = bp[nn];
                const int h = nn >> 6, hd = nn & 63;
                const int b = mbase >> 11, s0 = mbase & 2047;
                const size_t bh = (size_t)(b * H_ + h);
                if (n < 2048) {
                    __hip_bfloat16* dst = (n < 1024) ? Yq : Yk;
#pragma unroll
                    for (int r = 0; r < 4; ++r)
                        dst[(bh * S_ + s0 + r) * HD_ + hd] =
                            __float2bfloat16(acc[mi][ni][r] + bias);
                } else {
                    // Vt: 4 consecutive s at fixed hd -> one 8B store
                    union { __hip_bfloat16 hh[4]; ushort4 u4; } pk;
#pragma unroll
                    for (int r = 0; r < 4; ++r)
                        pk.hh[r] = __float2bfloat16(acc[mi][ni][r] + bias);
                    *reinterpret_cast<ushort4*>(&Yv[(bh * HD_ + hd) * S_ + s0]) = pk.u4;
                }
            } else {
#pragma unroll
                for (int r = 0; r < 4; ++r)
                    Yo[(size_t)(mbase + r) * N + n] = acc[mi][ni][r] + bias0[n];
            }
        }
    }
}

// K stage (wave-private): wave w stages rows [32w,32w+32) = exactly its read
// window. byte(row*128 + (X ^ ((row&7)<<4))) = K[row][X/2].
#define STAGE_K(dstc, t8v) do {                                                   \
    const int kt_ = (t8v) * 256;                                                  \
    _Pragma("unroll")                                                             \
    for (int i_ = 0; i_ < 4; ++i_) {                                              \
        const int chunk_ = w * 4 + i_;                                            \
        const int row_ = 8 * chunk_ + (l >> 3);                                   \
        const int col_ = ((l & 7) ^ ((l >> 3) & 7)) * 8;                          \
        __builtin_amdgcn_global_load_lds(                                         \
            (gbl_void*)(Kb + (size_t)(kt_ + row_) * HD_ + col_),                  \
            (lds_void*)((dstc) + chunk_ * 1024), 16, 0, 0);                       \
    }                                                                             \
} while (0)

// V stage (wave-private): wave w stages ALL 64 hd-rows x its 32-k (64B) window
// into its own 4KB slice, layout [64 rows][64B], slot s holds source byte
// s ^ ((row&3)<<4) of the window (read-side applies same XOR).
#define STAGE_VP(dstc, t8v) do {                                                  \
    const int kb_ = ((t8v) * 256 + 32 * w) * 2;                                   \
    _Pragma("unroll")                                                             \
    for (int i_ = 0; i_ < 4; ++i_) {                                              \
        const int row_ = 16 * i_ + (l >> 2);                                      \
        const int scol_ = ((l & 3) * 16) ^ ((row_ & 3) << 4);                     \
        __builtin_amdgcn_global_load_lds(                                         \
            (gbl_void*)((const char*)Vb + (size_t)row_ * (S_ * 2) + kb_ + scol_), \
            (lds_void*)((dstc) + w * 4096 + i_ * 1024), 16, 0, 0);                \
    }                                                                             \
} while (0)

// ---------------- fused attention: ZERO hot-loop barriers (r17, passing) ----------------
__global__ __launch_bounds__(512, 4) void attn_kernel(
    const __hip_bfloat16* __restrict__ Qh, const __hip_bfloat16* __restrict__ Kh,
    const __hip_bfloat16* __restrict__ Vt, const float* __restrict__ mask,
    float* __restrict__ probs, __hip_bfloat16* __restrict__ ctx) {
    union SMem {
        char KV[2][32768];       // per-wave 4KB slices x 8 waves, double-buffered
        float Cred[8][16][68];   // epilogue reduce (aliases)
    };
    __shared__ SMem sm;
    __shared__ float msk[2048];
    __shared__ float sred[8][16];
    __shared__ float invsh[16];

    const int bid = blockIdx.x;
    const int lg = (bid & 7) * 512 + (bid >> 3);   // bijective XCD swizzle
    const int qt = lg & 127;                        // S/16
    const int bh = lg >> 7;
    const int b = bh >> 4, h = bh & 15;
    const int t = threadIdx.x;
    const int w = t >> 6, l = t & 63, g = l >> 4, c = l & 15;
    const int q0 = qt * 16;
    const int kw = 32 * w;

    const __hip_bfloat16* Qb = Qh + (size_t)bh * S_ * HD_;
    const __hip_bfloat16* Kb = Kh + (size_t)bh * S_ * HD_;
    const __hip_bfloat16* Vb = Vt + (size_t)bh * HD_ * S_;
    const float* mrow = mask + (size_t)b * S_;

    *reinterpret_cast<float4*>(&msk[t * 4]) =
        *reinterpret_cast<const float4*>(&mrow[t * 4]);

    const bf16x8 aq0 = ldb8(&Qb[(q0 + c) * HD_ + g * 8]);
    const bf16x8 aq1 = ldb8(&Qb[(q0 + c) * HD_ + 32 + g * 8]);

    __syncthreads();   // msk visible; vmcnt queue drained -> exact counting

    unsigned int uA[8][2][2];
    float lsum = 0.f;

    // ---- pass 1: per-wave pipelined K tiles, NO barriers ----
    STAGE_K(sm.KV[0], 0);
#pragma unroll
    for (int t8 = 0; t8 < 8; ++t8) {
        const char* cur = sm.KV[t8 & 1];
        if (t8 < 7) {
            STAGE_K(sm.KV[(t8 & 1) ^ 1], t8 + 1);
            asm volatile("s_waitcnt vmcnt(4)" ::: "memory");
        } else {
            asm volatile("s_waitcnt vmcnt(0)" ::: "memory");
        }
        __builtin_amdgcn_sched_barrier(0);
        const int kt = t8 * 256;
#pragma unroll
        for (int ss = 0; ss < 2; ++ss) {
            const int krow = kw + ss * 16 + c;
            const char* kb2 = cur + krow * 128;
            const int sw = (krow & 7) << 4;
            const bf16x8 k0 = *reinterpret_cast<const bf16x8*>(kb2 + ((g * 16) ^ sw));
            const bf16x8 k1 = *reinterpret_cast<const bf16x8*>(kb2 + ((64 + g * 16) ^ sw));
            f32x4 aA = {};
            aA = mfma16(k0, aq0, aA);
            aA = mfma16(k1, aq1, aA);
            const float4 mk = *reinterpret_cast<const float4*>(&msk[kt + kw + ss * 16 + g * 4]);
            const float p0 = __expf(aA[0] * 0.125f + mk.x);
            const float p1 = __expf(aA[1] * 0.125f + mk.y);
            const float p2 = __expf(aA[2] * 0.125f + mk.z);
            const float p3 = __expf(aA[3] * 0.125f + mk.w);
            lsum += (p0 + p1) + (p2 + p3);
            union { __hip_bfloat16 hh[2]; unsigned int ui; } w0, w1;
            w0.hh[0] = __float2bfloat16(p0); w0.hh[1] = __float2bfloat16(p1);
            w1.hh[0] = __float2bfloat16(p2); w1.hh[1] = __float2bfloat16(p3);
            uA[t8][ss][0] = w0.ui; uA[t8][ss][1] = w1.ui;
        }
        __builtin_amdgcn_sched_barrier(0);
    }

    // ---- denominator seam (raw barrier; vmcnt queue empty after pass 1) ----
    lsum += __shfl_xor(lsum, 16);
    lsum += __shfl_xor(lsum, 32);
    if (g == 0) sred[w][c] = lsum;
    asm volatile("s_waitcnt lgkmcnt(0)" ::: "memory");
    __builtin_amdgcn_s_barrier();
    __builtin_amdgcn_sched_barrier(0);
    float tot = 0.f;
#pragma unroll
    for (int w8 = 0; w8 < 8; ++w8) tot += sred[w8][c];
    const float invA = 1.0f / tot;
    if (w == 0 && g == 0) invsh[c] = invA;

    // ---- pass 2: per-wave pipelined V tiles + probs stores, NO barriers ----
    f32x4 cacc[4] = {};
    float* prowA = probs + ((size_t)bh * S_ + q0 + c) * S_;
    const int src0 = 32 * (g & 1) + c;
    const int src1 = src0 + 16;
    const int sigma = g >> 1;
    STAGE_VP(sm.KV[0], 0);
#pragma unroll
    for (int t8 = 0; t8 < 8; ++t8) {
        const char* curV = sm.KV[t8 & 1] + w * 4096;
        if (t8 < 7) STAGE_VP(sm.KV[(t8 & 1) ^ 1], t8 + 1);
        // counted waits: loads(t) must land; ops-after = stores(t-1)(2)+loads(t+1)(4)
        if (t8 == 0)      asm volatile("s_waitcnt vmcnt(4)" ::: "memory");
        else if (t8 == 7) asm volatile("s_waitcnt vmcnt(2)" ::: "memory");
        else              asm volatile("s_waitcnt vmcnt(6)" ::: "memory");
        __builtin_amdgcn_sched_barrier(0);
        const int kt = t8 * 256;
#pragma unroll
        for (int ss = 0; ss < 2; ++ss) {
            f32x4 oA;
            oA[0] = __uint_as_float(uA[t8][ss][0] << 16) * invA;
            oA[1] = __uint_as_float(uA[t8][ss][0] & 0xffff0000u) * invA;
            oA[2] = __uint_as_float(uA[t8][ss][1] << 16) * invA;
            oA[3] = __uint_as_float(uA[t8][ss][1] & 0xffff0000u) * invA;
            *reinterpret_cast<f32x4*>(&prowA[kt + kw + ss * 16 + g * 4]) = oA;
        }
        union { unsigned int ui[4]; bf16x8 v; } afA;
        {
            const unsigned int x00 = __shfl(uA[t8][0][0], src0);
            const unsigned int x10 = __shfl(uA[t8][1][0], src0);
            const unsigned int x01 = __shfl(uA[t8][0][1], src0);
            const unsigned int x11 = __shfl(uA[t8][1][1], src0);
            const unsigned int x02 = __shfl(uA[t8][0][0], src1);
            const unsigned int x12 = __shfl(uA[t8][1][0], src1);
            const unsigned int x03 = __shfl(uA[t8][0][1], src1);
            const unsigned int x13 = __shfl(uA[t8][1][1], src1);
            afA.ui[0] = sigma ? x10 : x00;
            afA.ui[1] = sigma ? x11 : x01;
            afA.ui[2] = sigma ? x12 : x02;
            afA.ui[3] = sigma ? x13 : x03;
        }
#pragma unroll
        for (int n = 0; n < 4; ++n) {
            const int vrow = n * 16 + c;
            const bf16x8 bv = *reinterpret_cast<const bf16x8*>(
                curV + vrow * 64 + ((g * 16) ^ ((vrow & 3) << 4)));
            cacc[n] = mfma16(afA.v, bv, cacc[n]);
        }
        __builtin_amdgcn_sched_barrier(0);
    }

    // ---- cross-wave PV reduce (Cred aliases KV; full drain first) ----
    __syncthreads();
#pragma unroll
    for (int n = 0; n < 4; ++n)
#pragma unroll
        for (int r = 0; r < 4; ++r)
            sm.Cred[w][g * 4 + r][n * 16 + c] = cacc[n][r];
    __syncthreads();
    {
        const int row = t >> 5, col2 = (t & 31) * 2;
        float a0 = 0.f, a1 = 0.f;
#pragma unroll
        for (int w8 = 0; w8 < 8; ++w8) {
            const float2 vv = *reinterpret_cast<const float2*>(&sm.Cred[w8][row][col2]);
            a0 += vv.x; a1 += vv.y;
        }
        const float fin = invsh[row];
        union { __hip_bfloat16 hh[2]; unsigned int ui; } ov;
        ov.hh[0] = __float2bfloat16(a0 * fin);
        ov.hh[1] = __float2bfloat16(a1 * fin);
        *reinterpret_cast<unsigned int*>(
            &ctx[((size_t)b * S_ + q0 + row) * D_ + h * HD_ + col2]) = ov.ui;
    }
}

// ---------------- launch ----------------
extern "C" void kernel_launch(void* const* d_in, const int* in_sizes, int n_in,
                              void* d_out, int out_size, void* d_ws, size_t ws_size,
                              hipStream_t stream) {
    const float* hs   = (const float*)d_in[0];
    const float* mask = (const float*)d_in[1];
    const float* Wq   = (const float*)d_in[2];
    const float* bq   = (const float*)d_in[3];
    const float* Wk   = (const float*)d_in[4];
    const float* bk   = (const float*)d_in[5];
    const float* Wv   = (const float*)d_in[6];
    const float* bv   = (const float*)d_in[7];
    const float* Wo   = (const float*)d_in[8];
    const float* bo   = (const float*)d_in[9];

    float* out   = (float*)d_out;
    float* probs = out + (size_t)B_ * S_ * D_;

    const size_t MD = (size_t)B_ * S_ * D_;
    __hip_bfloat16* hsb   = (__hip_bfloat16*)d_ws;
    __hip_bfloat16* wqkvb = hsb + MD;
    __hip_bfloat16* wob   = wqkvb + 3u * 1024u * 1024u;
    __hip_bfloat16* Qh    = wob + (size_t)1024 * 1024;
    __hip_bfloat16* Kh    = Qh + MD;
    __hip_bfloat16* Vt    = Kh + MD;
    __hip_bfloat16* ctxb  = Vt + MD;

    conv_all<<<8192, 256, 0, stream>>>(hs, Wq, Wk, Wv, Wo, hsb, wqkvb, wob);

    gemm_bt<0><<<32 * 24, 256, 0, stream>>>(hsb, wqkvb, bq, bk, bv,
                                            Qh, Kh, Vt, nullptr, 4096, 3072, 1024);

    attn_kernel<<<B_ * H_ * (S_ / 16), 512, 0, stream>>>(Qh, Kh, Vt, mask, probs, ctxb);

    gemm_bt<1><<<32 * 8, 256, 0, stream>>>(ctxb, wob, bo, nullptr, nullptr,
                                           nullptr, nullptr, nullptr, out, 4096, 1024, 1024);
}

// Round 19
// 264.591 us; speedup vs baseline: 1.3916x; 1.0313x over previous
//
#include <hip/hip_runtime.h>
#include <hip/hip_bf16.h>

#define B_ 2
#define S_ 2048
#define D_ 1024
#define H_ 16
#define HD_ 64

typedef short bf16x8 __attribute__((ext_vector_type(8)));
typedef float f32x4 __attribute__((ext_vector_type(4)));

typedef __attribute__((address_space(3))) void lds_void;
typedef const __attribute__((address_space(1))) void gbl_void;

__device__ __forceinline__ f32x4 mfma16(bf16x8 a, bf16x8 b, f32x4 c) {
    return __builtin_amdgcn_mfma_f32_16x16x32_bf16(a, b, c, 0, 0, 0);
}

__device__ __forceinline__ bf16x8 ldb8(const __hip_bfloat16* p) {
    return *reinterpret_cast<const bf16x8*>(p);
}

// ---------------- fused fp32 -> bf16 conversion (ALL tensors, one launch) ----------------
__global__ __launch_bounds__(256) void conv_all(
    const float* __restrict__ hs, const float* __restrict__ Wq,
    const float* __restrict__ Wk, const float* __restrict__ Wv,
    const float* __restrict__ Wo,
    __hip_bfloat16* __restrict__ hsb, __hip_bfloat16* __restrict__ wqkvb,
    __hip_bfloat16* __restrict__ wob) {
    const int i = blockIdx.x * 256 + threadIdx.x;
    const float* src;
    __hip_bfloat16* dst;
    int off;
    if (i < (1 << 20)) {
        src = hs; dst = hsb; off = i;
    } else {
        const int j = i - (1 << 20);
        const int r = j >> 18;             // 262144 float4 per weight
        off = j & 0x3ffff;
        src = (r == 0) ? Wq : (r == 1) ? Wk : (r == 2) ? Wv : Wo;
        dst = (r < 3) ? wqkvb + (size_t)r * 1048576 : wob;
    }
    float4 f = reinterpret_cast<const float4*>(src)[off];
    union { __hip_bfloat16 h[4]; ushort4 u; } cv;
    cv.h[0] = __float2bfloat16(f.x);
    cv.h[1] = __float2bfloat16(f.y);
    cv.h[2] = __float2bfloat16(f.z);
    cv.h[3] = __float2bfloat16(f.w);
    reinterpret_cast<ushort4*>(dst)[off] = cv.u;
}

// ---------------- GEMM: BK=64, XOR-swizzled LDS (conflict-free reads) ----------------
// LDS layout: row-major [128][64] bf16 (128B rows); 16B slot s of row holds
// source chunk s ^ (row&7)  (pre-swizzled global source; read applies same XOR).
// MODE 0 epilogue: Q (n<1024) -> Qt[bh][hd][s] ushort4; K scatter; V -> Vt ushort4.
template <int MODE>
__global__ __launch_bounds__(256) void gemm_bt(
    const __hip_bfloat16* __restrict__ X, const __hip_bfloat16* __restrict__ Wt,
    const float* __restrict__ bias0, const float* __restrict__ bias1,
    const float* __restrict__ bias2,
    __hip_bfloat16* __restrict__ Yq, __hip_bfloat16* __restrict__ Yk,
    __hip_bfloat16* __restrict__ Yv, float* __restrict__ Yo,
    int M, int N, int K) {
    __shared__ __hip_bfloat16 As[128 * 64];
    __shared__ __hip_bfloat16 Bs[128 * 64];

    const int ntn = N >> 7;
    const int nwg = (M >> 7) * ntn;
    const int cpx = nwg >> 3;
    const int bid = blockIdx.x;
    const int lg = (bid & 7) * cpx + (bid >> 3);
    const int tm = lg / ntn;
    const int tn = lg % ntn;
    const int t = threadIdx.x;
    const int w = t >> 6, l = t & 63, g = l >> 4, c = l & 15;
    const int wr = w >> 1, wc = w & 1;

    const int srow = t >> 3;          // 0..31
    const int schunk = t & 7;         // 16B chunk slot within 128B row

    f32x4 acc[4][4] = {};

    for (int k0 = 0; k0 < K; k0 += 64) {
        __syncthreads();
#pragma unroll
        for (int j = 0; j < 4; ++j) {
            const int row = j * 32 + srow;
            const int se = (schunk ^ (row & 7)) * 8;   // pre-swizzled source elem
            __builtin_amdgcn_global_load_lds(
                (gbl_void*)(X + (size_t)(tm * 128 + row) * K + k0 + se),
                (lds_void*)(As + (j * 32 + w * 8) * 64), 16, 0, 0);
            __builtin_amdgcn_global_load_lds(
                (gbl_void*)(Wt + (size_t)(tn * 128 + row) * K + k0 + se),
                (lds_void*)(Bs + (j * 32 + w * 8) * 64), 16, 0, 0);
        }
        __syncthreads();

#pragma unroll
        for (int kh = 0; kh < 2; ++kh) {
            bf16x8 am[4], bn[4];
#pragma unroll
            for (int mi = 0; mi < 4; ++mi) {
                const int row = wr * 64 + mi * 16 + c;
                am[mi] = *reinterpret_cast<const bf16x8*>(
                    reinterpret_cast<const char*>(As) + row * 128 +
                    ((kh * 64 + g * 16) ^ ((row & 7) << 4)));
            }
#pragma unroll
            for (int ni = 0; ni < 4; ++ni) {
                const int row = wc * 64 + ni * 16 + c;
                bn[ni] = *reinterpret_cast<const bf16x8*>(
                    reinterpret_cast<const char*>(Bs) + row * 128 +
                    ((kh * 64 + g * 16) ^ ((row & 7) << 4)));
            }
#pragma unroll
            for (int mi = 0; mi < 4; ++mi)
#pragma unroll
                for (int ni = 0; ni < 4; ++ni)
                    acc[mi][ni] = mfma16(am[mi], bn[ni], acc[mi][ni]);
        }
    }

#pragma unroll
    for (int mi = 0; mi < 4; ++mi) {
        const int mbase = tm * 128 + wr * 64 + mi * 16 + g * 4;
#pragma unroll
        for (int ni = 0; ni < 4; ++ni) {
            const int n = tn * 128 + wc * 64 + ni * 16 + c;
            if (MODE == 0) {
                const float* bp = (n < 1024) ? bias0 : (n < 2048) ? bias1 : bias2;
                const int nn = n & 1023;
                const float bias = bp[nn];
                const int h = nn >> 6, hd = nn & 63;
                const int b = mbase >> 11, s0 = mbase & 2047;
                const size_t bh = (size_t)(b * H_ + h);
                if (n < 1024 || n >= 2048) {
                    // Qt / Vt: transposed [bh][hd][s] -> 4 consecutive s = one 8B store
                    __hip_bfloat16* dst = (n < 1024) ? Yq : Yv;
                    union { __hip_bfloat16 hh[4]; ushort4 u4; } pk;
#pragma unroll
                    for (int r = 0; r < 4; ++r)
                        pk.hh[r] = __float2bfloat16(acc[mi][ni][r] + bias);
                    *reinterpret_cast<ushort4*>(&dst[(bh * HD_ + hd) * S_ + s0]) = pk.u4;
                } else {
#pragma unroll
                    for (int r = 0; r < 4; ++r)
                        Yk[(bh * S_ + s0 + r) * HD_ + hd] =
                            __float2bfloat16(acc[mi][ni][r] + bias);
                }
            } else {
#pragma unroll
                for (int r = 0; r < 4; ++r)
                    Yo[(size_t)(mbase + r) * N + n] = acc[mi][ni][r] + bias0[n];
            }
        }
    }
}

// K stage (wave-private): wave w stages rows [32w,32w+32) = exactly its read
// window. byte(row*128 + (X ^ ((row&7)<<4))) = K[row][X/2].
#define STAGE_K(dstc, t8v) do {                                                   \
    const int kt_ = (t8v) * 256;                                                  \
    _Pragma("unroll")                                                             \
    for (int i_ = 0; i_ < 4; ++i_) {                                              \
        const int chunk_ = w * 4 + i_;                                            \
        const int row_ = 8 * chunk_ + (l >> 3);                                   \
        const int col_ = ((l & 7) ^ ((l >> 3) & 7)) * 8;                          \
        __builtin_amdgcn_global_load_lds(                                         \
            (gbl_void*)(Kb + (size_t)(kt_ + row_) * HD_ + col_),                  \
            (lds_void*)((dstc) + chunk_ * 1024), 16, 0, 0);                       \
    }                                                                             \
} while (0)

// V stage (wave-private): wave w stages ALL 64 hd-rows x its 32-k (64B) window
// into its own 4KB slice, layout [64 rows][64B], slot s holds source byte
// s ^ ((row&3)<<4) of the window (read-side applies same XOR).
#define STAGE_VP(dstc, t8v) do {                                                  \
    const int kb_ = ((t8v) * 256 + 32 * w) * 2;                                   \
    _Pragma("unroll")                                                             \
    for (int i_ = 0; i_ < 4; ++i_) {                                              \
        const int row_ = 16 * i_ + (l >> 2);                                      \
        const int scol_ = ((l & 3) * 16) ^ ((row_ & 3) << 4);                     \
        __builtin_amdgcn_global_load_lds(                                         \
            (gbl_void*)((const char*)Vb + (size_t)row_ * (S_ * 2) + kb_ + scol_), \
            (lds_void*)((dstc) + w * 4096 + i_ * 1024), 16, 0, 0);                \
    }                                                                             \
} while (0)

// ---------------- fused attention: ZERO hot-loop barriers (r17, passing) ----------------
// Q now read from TRANSPOSED Qt[bh][hd][s] (16 one-time strided ushort loads).
__global__ __launch_bounds__(512, 4) void attn_kernel(
    const __hip_bfloat16* __restrict__ Qt, const __hip_bfloat16* __restrict__ Kh,
    const __hip_bfloat16* __restrict__ Vt, const float* __restrict__ mask,
    float* __restrict__ probs, __hip_bfloat16* __restrict__ ctx) {
    union SMem {
        char KV[2][32768];       // per-wave 4KB slices x 8 waves, double-buffered
        float Cred[8][16][68];   // epilogue reduce (aliases)
    };
    __shared__ SMem sm;
    __shared__ float msk[2048];
    __shared__ float sred[8][16];
    __shared__ float invsh[16];

    const int bid = blockIdx.x;
    const int lg = (bid & 7) * 512 + (bid >> 3);   // bijective XCD swizzle
    const int qt = lg & 127;                        // S/16
    const int bh = lg >> 7;
    const int b = bh >> 4, h = bh & 15;
    const int t = threadIdx.x;
    const int w = t >> 6, l = t & 63, g = l >> 4, c = l & 15;
    const int q0 = qt * 16;
    const int kw = 32 * w;

    const __hip_bfloat16* Qb = Qt + (size_t)bh * HD_ * S_;
    const __hip_bfloat16* Kb = Kh + (size_t)bh * S_ * HD_;
    const __hip_bfloat16* Vb = Vt + (size_t)bh * HD_ * S_;
    const float* mrow = mask + (size_t)b * S_;

    *reinterpret_cast<float4*>(&msk[t * 4]) =
        *reinterpret_cast<const float4*>(&mrow[t * 4]);

    // Q fragments from transposed layout: hd = 8g+e (aq0), 32+8g+e (aq1); s = q0+c
    union { ushort us[8]; bf16x8 v; } q0u, q1u;
#pragma unroll
    for (int e = 0; e < 8; ++e) {
        q0u.us[e] = *reinterpret_cast<const ushort*>(&Qb[(size_t)(8 * g + e) * S_ + q0 + c]);
        q1u.us[e] = *reinterpret_cast<const ushort*>(&Qb[(size_t)(32 + 8 * g + e) * S_ + q0 + c]);
    }
    const bf16x8 aq0 = q0u.v;
    const bf16x8 aq1 = q1u.v;

    __syncthreads();   // msk visible; vmcnt queue drained -> exact counting

    unsigned int uA[8][2][2];
    float lsum = 0.f;

    // ---- pass 1: per-wave pipelined K tiles, NO barriers ----
    STAGE_K(sm.KV[0], 0);
#pragma unroll
    for (int t8 = 0; t8 < 8; ++t8) {
        const char* cur = sm.KV[t8 & 1];
        if (t8 < 7) {
            STAGE_K(sm.KV[(t8 & 1) ^ 1], t8 + 1);
            asm volatile("s_waitcnt vmcnt(4)" ::: "memory");
        } else {
            asm volatile("s_waitcnt vmcnt(0)" ::: "memory");
        }
        __builtin_amdgcn_sched_barrier(0);
        const int kt = t8 * 256;
#pragma unroll
        for (int ss = 0; ss < 2; ++ss) {
            const int krow = kw + ss * 16 + c;
            const char* kb2 = cur + krow * 128;
            const int sw = (krow & 7) << 4;
            const bf16x8 k0 = *reinterpret_cast<const bf16x8*>(kb2 + ((g * 16) ^ sw));
            const bf16x8 k1 = *reinterpret_cast<const bf16x8*>(kb2 + ((64 + g * 16) ^ sw));
            f32x4 aA = {};
            aA = mfma16(k0, aq0, aA);
            aA = mfma16(k1, aq1, aA);
            const float4 mk = *reinterpret_cast<const float4*>(&msk[kt + kw + ss * 16 + g * 4]);
            const float p0 = __expf(aA[0] * 0.125f + mk.x);
            const float p1 = __expf(aA[1] * 0.125f + mk.y);
            const float p2 = __expf(aA[2] * 0.125f + mk.z);
            const float p3 = __expf(aA[3] * 0.125f + mk.w);
            lsum += (p0 + p1) + (p2 + p3);
            union { __hip_bfloat16 hh[2]; unsigned int ui; } w0, w1;
            w0.hh[0] = __float2bfloat16(p0); w0.hh[1] = __float2bfloat16(p1);
            w1.hh[0] = __float2bfloat16(p2); w1.hh[1] = __float2bfloat16(p3);
            uA[t8][ss][0] = w0.ui; uA[t8][ss][1] = w1.ui;
        }
        __builtin_amdgcn_sched_barrier(0);
    }

    // ---- denominator seam (raw barrier; vmcnt queue empty after pass 1) ----
    lsum += __shfl_xor(lsum, 16);
    lsum += __shfl_xor(lsum, 32);
    if (g == 0) sred[w][c] = lsum;
    asm volatile("s_waitcnt lgkmcnt(0)" ::: "memory");
    __builtin_amdgcn_s_barrier();
    __builtin_amdgcn_sched_barrier(0);
    float tot = 0.f;
#pragma unroll
    for (int w8 = 0; w8 < 8; ++w8) tot += sred[w8][c];
    const float invA = 1.0f / tot;
    if (w == 0 && g == 0) invsh[c] = invA;

    // ---- pass 2: per-wave pipelined V tiles + probs stores, NO barriers ----
    f32x4 cacc[4] = {};
    float* prowA = probs + ((size_t)bh * S_ + q0 + c) * S_;
    const int src0 = 32 * (g & 1) + c;
    const int src1 = src0 + 16;
    const int sigma = g >> 1;
    STAGE_VP(sm.KV[0], 0);
#pragma unroll
    for (int t8 = 0; t8 < 8; ++t8) {
        const char* curV = sm.KV[t8 & 1] + w * 4096;
        if (t8 < 7) STAGE_VP(sm.KV[(t8 & 1) ^ 1], t8 + 1);
        // counted waits: loads(t) must land; ops-after = stores(t-1)(2)+loads(t+1)(4)
        if (t8 == 0)      asm volatile("s_waitcnt vmcnt(4)" ::: "memory");
        else if (t8 == 7) asm volatile("s_waitcnt vmcnt(2)" ::: "memory");
        else              asm volatile("s_waitcnt vmcnt(6)" ::: "memory");
        __builtin_amdgcn_sched_barrier(0);
        const int kt = t8 * 256;
#pragma unroll
        for (int ss = 0; ss < 2; ++ss) {
            f32x4 oA;
            oA[0] = __uint_as_float(uA[t8][ss][0] << 16) * invA;
            oA[1] = __uint_as_float(uA[t8][ss][0] & 0xffff0000u) * invA;
            oA[2] = __uint_as_float(uA[t8][ss][1] << 16) * invA;
            oA[3] = __uint_as_float(uA[t8][ss][1] & 0xffff0000u) * invA;
            *reinterpret_cast<f32x4*>(&prowA[kt + kw + ss * 16 + g * 4]) = oA;
        }
        union { unsigned int ui[4]; bf16x8 v; } afA;
        {
            const unsigned int x00 = __shfl(uA[t8][0][0], src0);
            const unsigned int x10 = __shfl(uA[t8][1][0], src0);
            const unsigned int x01 = __shfl(uA[t8][0][1], src0);
            const unsigned int x11 = __shfl(uA[t8][1][1], src0);
            const unsigned int x02 = __shfl(uA[t8][0][0], src1);
            const unsigned int x12 = __shfl(uA[t8][1][0], src1);
            const unsigned int x03 = __shfl(uA[t8][0][1], src1);
            const unsigned int x13 = __shfl(uA[t8][1][1], src1);
            afA.ui[0] = sigma ? x10 : x00;
            afA.ui[1] = sigma ? x11 : x01;
            afA.ui[2] = sigma ? x12 : x02;
            afA.ui[3] = sigma ? x13 : x03;
        }
#pragma unroll
        for (int n = 0; n < 4; ++n) {
            const int vrow = n * 16 + c;
            const bf16x8 bv = *reinterpret_cast<const bf16x8*>(
                curV + vrow * 64 + ((g * 16) ^ ((vrow & 3) << 4)));
            cacc[n] = mfma16(afA.v, bv, cacc[n]);
        }
        __builtin_amdgcn_sched_barrier(0);
    }

    // ---- cross-wave PV reduce (Cred aliases KV; full drain first) ----
    __syncthreads();
#pragma unroll
    for (int n = 0; n < 4; ++n)
#pragma unroll
        for (int r = 0; r < 4; ++r)
            sm.Cred[w][g * 4 + r][n * 16 + c] = cacc[n][r];
    __syncthreads();
    {
        const int row = t >> 5, col2 = (t & 31) * 2;
        float a0 = 0.f, a1 = 0.f;
#pragma unroll
        for (int w8 = 0; w8 < 8; ++w8) {
            const float2 vv = *reinterpret_cast<const float2*>(&sm.Cred[w8][row][col2]);
            a0 += vv.x; a1 += vv.y;
        }
        const float fin = invsh[row];
        union { __hip_bfloat16 hh[2]; unsigned int ui; } ov;
        ov.hh[0] = __float2bfloat16(a0 * fin);
        ov.hh[1] = __float2bfloat16(a1 * fin);
        *reinterpret_cast<unsigned int*>(
            &ctx[((size_t)b * S_ + q0 + row) * D_ + h * HD_ + col2]) = ov.ui;
    }
}

// ---------------- launch ----------------
extern "C" void kernel_launch(void* const* d_in, const int* in_sizes, int n_in,
                              void* d_out, int out_size, void* d_ws, size_t ws_size,
                              hipStream_t stream) {
    const float* hs   = (const float*)d_in[0];
    const float* mask = (const float*)d_in[1];
    const float* Wq   = (const float*)d_in[2];
    const float* bq   = (const float*)d_in[3];
    const float* Wk   = (const float*)d_in[4];
    const float* bk   = (const float*)d_in[5];
    const float* Wv   = (const float*)d_in[6];
    const float* bv   = (const float*)d_in[7];
    const float* Wo   = (const float*)d_in[8];
    const float* bo   = (const float*)d_in[9];

    float* out   = (float*)d_out;
    float* probs = out + (size_t)B_ * S_ * D_;

    const size_t MD = (size_t)B_ * S_ * D_;
    __hip_bfloat16* hsb   = (__hip_bfloat16*)d_ws;
    __hip_bfloat16* wqkvb = hsb + MD;
    __hip_bfloat16* wob   = wqkvb + 3u * 1024u * 1024u;
    __hip_bfloat16* Qtb   = wob + (size_t)1024 * 1024;   // TRANSPOSED [bh][hd][s]
    __hip_bfloat16* Kh    = Qtb + MD;
    __hip_bfloat16* Vt    = Kh + MD;
    __hip_bfloat16* ctxb  = Vt + MD;

    conv_all<<<8192, 256, 0, stream>>>(hs, Wq, Wk, Wv, Wo, hsb, wqkvb, wob);

    gemm_bt<0><<<32 * 24, 256, 0, stream>>>(hsb, wqkvb, bq, bk, bv,
                                            Qtb, Kh, Vt, nullptr, 4096, 3072, 1024);

    attn_kernel<<<B_ * H_ * (S_ / 16), 512, 0, stream>>>(Qtb, Kh, Vt, mask, probs, ctxb);

    gemm_bt<1><<<32 * 8, 256, 0, stream>>>(ctxb, wob, bo, nullptr, nullptr,
                                           nullptr, nullptr, nullptr, out, 4096, 1024, 1024);
}